// Round 1
// baseline (434.035 us; speedup 1.0000x reference)
//
#include <hip/hip_runtime.h>
#include <stdint.h>

#define T_TOK 4096
#define H_DIM 1024
#define E_NUM 16
#define I_DIM 512
#define IS_DIM 2048
#define TOPK 4
#define NGRP 4
#define GSZ 4
#define MAXMT 32

typedef unsigned short u16;
typedef __attribute__((ext_vector_type(8))) short short8;
typedef __attribute__((ext_vector_type(4))) float f32x4;

__device__ __forceinline__ void gload16(const void* g, void* l) {
  __builtin_amdgcn_global_load_lds(
      (const __attribute__((address_space(1))) void*)g,
      (__attribute__((address_space(3))) void*)l, 16, 0, 0);
}

__device__ __forceinline__ u16 f2bf(float f) {
  union { float f; uint32_t u; } v; v.f = f;
  uint32_t u = v.u;
  uint32_t r = (u + 0x7fffu + ((u >> 16) & 1u)) >> 16;
  return (u16)r;
}

// ---------------- fp32 -> bf16 conversion ----------------
__global__ __launch_bounds__(256) void cvt_bf16_kernel(const float* __restrict__ in,
                                                       u16* __restrict__ out, int n4) {
  int i = blockIdx.x * 256 + threadIdx.x;
  if (i >= n4) return;
  float4 v = reinterpret_cast<const float4*>(in)[i];
  ushort4 o;
  o.x = f2bf(v.x); o.y = f2bf(v.y); o.z = f2bf(v.z); o.w = f2bf(v.w);
  reinterpret_cast<ushort4*>(out)[i] = o;
}

// ---------------- routing ----------------
__global__ __launch_bounds__(256) void route_kernel(
    const float* __restrict__ x, const float* __restrict__ rw,
    const float* __restrict__ bias, int* __restrict__ counts,
    int* __restrict__ tok_list, float* __restrict__ w_list) {
  const int wave = threadIdx.x >> 6;
  const int lane = threadIdx.x & 63;
  const int t = blockIdx.x * 4 + wave;

  double acc[E_NUM];
#pragma unroll
  for (int e = 0; e < E_NUM; ++e) acc[e] = 0.0;
  const float* xr = x + (size_t)t * H_DIM;
  for (int j = 0; j < H_DIM / 64; ++j) {
    float xv = xr[lane + j * 64];
#pragma unroll
    for (int e = 0; e < E_NUM; ++e)
      acc[e] += (double)xv * (double)rw[e * H_DIM + lane + j * 64];
  }
#pragma unroll
  for (int e = 0; e < E_NUM; ++e) {
#pragma unroll
    for (int off = 32; off; off >>= 1) acc[e] += __shfl_xor(acc[e], off);
  }
  if (lane == 0) {
    float scores[E_NUM], sfc[E_NUM];
#pragma unroll
    for (int e = 0; e < E_NUM; ++e) {
      scores[e] = 1.0f / (1.0f + expf((float)(-acc[e])));
      sfc[e] = scores[e] + bias[e];
    }
    float gs[NGRP];
#pragma unroll
    for (int g = 0; g < NGRP; ++g) {
      float m1 = -1e30f, m2 = -1e30f;
#pragma unroll
      for (int j = 0; j < GSZ; ++j) {
        float v = sfc[g * GSZ + j];
        if (v > m1) { m2 = m1; m1 = v; } else if (v > m2) { m2 = v; }
      }
      gs[g] = m1 + m2;
    }
    int g1 = 0;
    for (int g = 1; g < NGRP; ++g) if (gs[g] > gs[g1]) g1 = g;
    int g2 = -1;
    for (int g = 0; g < NGRP; ++g) {
      if (g == g1) continue;
      if (g2 < 0 || gs[g] > gs[g2]) g2 = g;
    }
    float masked[E_NUM];
#pragma unroll
    for (int e = 0; e < E_NUM; ++e) {
      int g = e / GSZ;
      masked[e] = (g == g1 || g == g2) ? sfc[e] : 0.0f;
    }
    int tidx[TOPK]; float tw[TOPK];
#pragma unroll
    for (int k = 0; k < TOPK; ++k) {
      int best = 0; float bv = masked[0];
      for (int e = 1; e < E_NUM; ++e)
        if (masked[e] > bv) { bv = masked[e]; best = e; }
      tidx[k] = best; tw[k] = scores[best]; masked[best] = -1e30f;
    }
    float s = tw[0] + tw[1] + tw[2] + tw[3] + 1e-20f;
#pragma unroll
    for (int k = 0; k < TOPK; ++k) {
      float wv = tw[k] / s * 2.5f;
      int e = tidx[k];
      int pos = atomicAdd(&counts[e], 1);
      tok_list[e * T_TOK + pos] = t;
      w_list[e * T_TOK + pos] = wv;
    }
  }
}

__global__ void prefix_kernel(const int* __restrict__ counts, int* __restrict__ offsets) {
  if (threadIdx.x == 0) {
    int s = 0;
    for (int e = 0; e < E_NUM; ++e) { offsets[e] = s; s += counts[e]; }
    offsets[E_NUM] = s;
  }
}

// ---------------- bf16 MFMA GEMM: C = A * B^T ----------------
// A [M,K] bf16 row-major (optionally gathered rows), B [N,K] bf16 row-major.
// EPI 0: shared-up   : C=hs bf16, relu^2
// EPI 1: shared-down : C=out fp32 plain store
// EPI 2: routed-up   : A gathered by token list, C=h_pairs bf16, relu^2 * w
// EPI 3: routed-down : C scattered by token list, fp32 atomicAdd into out
template <int EPI>
__global__ __launch_bounds__(256) void gemm_bt(
    const u16* __restrict__ Abase, const u16* __restrict__ Bbase,
    float* __restrict__ Cf, u16* __restrict__ Cb,
    int M, int N, int K,
    const int* __restrict__ counts, const int* __restrict__ offsets,
    const int* __restrict__ tok_list, const float* __restrict__ w_list) {
  __shared__ __align__(16) u16 As[128 * 32];
  __shared__ __align__(16) u16 Bs[128 * 32];

  const int NT = N >> 7;
  int mt, nt, cnt = M, obase = 0;
  const int* toks = nullptr;
  const float* rww = nullptr;
  const u16* A = Abase;
  const u16* B = Bbase;

  if constexpr (EPI <= 1) {
    mt = blockIdx.x / NT;
    nt = blockIdx.x - mt * NT;
  } else {
    const int per_e = MAXMT * NT;
    int e = blockIdx.x / per_e;
    int r = blockIdx.x - e * per_e;
    mt = r / NT;
    nt = r - mt * NT;
    cnt = counts[e];
    if (mt * 128 >= cnt) return;
    obase = offsets[e];
    toks = tok_list + e * T_TOK;
    rww = w_list + e * T_TOK;
    if constexpr (EPI == 2) {
      B = Bbase + (size_t)e * (I_DIM * H_DIM);
    } else {
      A = Abase + (size_t)obase * I_DIM;
      B = Bbase + (size_t)e * (H_DIM * I_DIM);
    }
  }

  const int tid = threadIdx.x;
  const int srow = tid >> 2;
  const int skcol = (tid & 3) << 3;
  const u16* gA[2];
  const u16* gB[2];
#pragma unroll
  for (int p = 0; p < 2; ++p) {
    int row = srow + (p << 6);
    int am = mt * 128 + row;
    if constexpr (EPI == 2) {
      int tk = toks[(am < cnt) ? am : 0];
      gA[p] = Abase + (size_t)tk * H_DIM + skcol;
    } else if constexpr (EPI == 3) {
      int ar = (am < cnt) ? am : 0;
      gA[p] = A + (size_t)ar * K + skcol;
    } else {
      gA[p] = A + (size_t)am * K + skcol;
    }
    gB[p] = B + (size_t)(nt * 128 + row) * K + skcol;
  }

  const int wave = tid >> 6;
  const int lane = tid & 63;
  const int wrow = (wave >> 1) << 6;
  const int wcol = (wave & 1) << 6;
  const int frow = lane & 15;
  const int fk = (lane >> 4) << 3;

  f32x4 acc[4][4];
#pragma unroll
  for (int m = 0; m < 4; ++m)
#pragma unroll
    for (int n = 0; n < 4; ++n) acc[m][n] = (f32x4)0.0f;

  u16* asw = &As[tid << 3];
  u16* bsw = &Bs[tid << 3];
  const u16* ar0 = &As[(wrow + frow) * 32 + fk];
  const u16* br0 = &Bs[(wcol + frow) * 32 + fk];

  for (int k0 = 0; k0 < K; k0 += 32) {
#pragma unroll
    for (int p = 0; p < 2; ++p) {
      gload16(gA[p] + k0, asw + (p << 11));
      gload16(gB[p] + k0, bsw + (p << 11));
    }
    __syncthreads();
    short8 a[4], b[4];
#pragma unroll
    for (int m = 0; m < 4; ++m)
      a[m] = *reinterpret_cast<const short8*>(ar0 + (m << 4) * 32);
#pragma unroll
    for (int n = 0; n < 4; ++n)
      b[n] = *reinterpret_cast<const short8*>(br0 + (n << 4) * 32);
#pragma unroll
    for (int m = 0; m < 4; ++m)
#pragma unroll
      for (int n = 0; n < 4; ++n)
        acc[m][n] = __builtin_amdgcn_mfma_f32_16x16x32_bf16(a[m], b[n], acc[m][n], 0, 0, 0);
    __syncthreads();
  }

  const int rbase = (lane >> 4) << 2;
  const int cbase = lane & 15;
#pragma unroll
  for (int m = 0; m < 4; ++m) {
#pragma unroll
    for (int r = 0; r < 4; ++r) {
      int lr = wrow + (m << 4) + rbase + r;
      int grow = mt * 128 + lr;
      if (EPI >= 2 && grow >= cnt) continue;
      float wv = 1.0f;
      int orow = grow;
      if constexpr (EPI == 2) wv = rww[grow];
      if constexpr (EPI == 3) orow = toks[grow];
#pragma unroll
      for (int n = 0; n < 4; ++n) {
        int gc = nt * 128 + wcol + (n << 4) + cbase;
        float v = acc[m][n][r];
        if constexpr (EPI == 0) {
          float tpos = fmaxf(v, 0.0f);
          Cb[(size_t)grow * N + gc] = f2bf(tpos * tpos);
        } else if constexpr (EPI == 1) {
          Cf[(size_t)grow * N + gc] = v;
        } else if constexpr (EPI == 2) {
          float tpos = fmaxf(v, 0.0f);
          Cb[(size_t)(obase + grow) * I_DIM + gc] = f2bf(tpos * tpos * wv);
        } else {
          atomicAdd(&Cf[(size_t)orow * H_DIM + gc], v);
        }
      }
    }
  }
}

// ---------------- launch ----------------
extern "C" void kernel_launch(void* const* d_in, const int* in_sizes, int n_in,
                              void* d_out, int out_size, void* d_ws, size_t ws_size,
                              hipStream_t stream) {
  const float* x = (const float*)d_in[0];
  const float* rw = (const float*)d_in[1];
  const float* bias = (const float*)d_in[2];
  const float* w_up = (const float*)d_in[3];
  const float* w_down = (const float*)d_in[4];
  const float* ws_up = (const float*)d_in[5];
  const float* ws_down = (const float*)d_in[6];
  float* out = (float*)d_out;

  uint8_t* wsb = (uint8_t*)d_ws;
  size_t off = 0;
  auto alloc = [&](size_t bytes) {
    void* p = wsb + off;
    off += (bytes + 255) & ~(size_t)255;
    return p;
  };
  u16* x_bf = (u16*)alloc((size_t)T_TOK * H_DIM * 2);
  u16* wsup_bf = (u16*)alloc((size_t)IS_DIM * H_DIM * 2);
  u16* wsdn_bf = (u16*)alloc((size_t)H_DIM * IS_DIM * 2);
  u16* wup_bf = (u16*)alloc((size_t)E_NUM * I_DIM * H_DIM * 2);
  u16* wdn_bf = (u16*)alloc((size_t)E_NUM * H_DIM * I_DIM * 2);
  u16* hs = (u16*)alloc((size_t)T_TOK * IS_DIM * 2);
  u16* hp = (u16*)alloc((size_t)(T_TOK * TOPK + 128) * I_DIM * 2);
  int* counts = (int*)alloc(64);
  int* offsets = (int*)alloc(128);
  int* tok_list = (int*)alloc((size_t)E_NUM * T_TOK * 4);
  float* w_list = (float*)alloc((size_t)E_NUM * T_TOK * 4);

  hipMemsetAsync(counts, 0, 64, stream);

  int n4;
  n4 = T_TOK * H_DIM / 4;
  cvt_bf16_kernel<<<(n4 + 255) / 256, 256, 0, stream>>>(x, x_bf, n4);
  n4 = IS_DIM * H_DIM / 4;
  cvt_bf16_kernel<<<(n4 + 255) / 256, 256, 0, stream>>>(ws_up, wsup_bf, n4);
  n4 = H_DIM * IS_DIM / 4;
  cvt_bf16_kernel<<<(n4 + 255) / 256, 256, 0, stream>>>(ws_down, wsdn_bf, n4);
  n4 = E_NUM * I_DIM * H_DIM / 4;
  cvt_bf16_kernel<<<(n4 + 255) / 256, 256, 0, stream>>>(w_up, wup_bf, n4);
  n4 = E_NUM * H_DIM * I_DIM / 4;
  cvt_bf16_kernel<<<(n4 + 255) / 256, 256, 0, stream>>>(w_down, wdn_bf, n4);

  route_kernel<<<T_TOK / 4, 256, 0, stream>>>(x, rw, bias, counts, tok_list, w_list);
  prefix_kernel<<<1, 64, 0, stream>>>(counts, offsets);

  // shared up: [T,H] x [IS,H]^T -> hs [T,IS] (relu^2, bf16)
  gemm_bt<0><<<(T_TOK / 128) * (IS_DIM / 128), 256, 0, stream>>>(
      x_bf, wsup_bf, nullptr, hs, T_TOK, IS_DIM, H_DIM,
      nullptr, nullptr, nullptr, nullptr);
  // shared down: [T,IS] x [H,IS]^T -> out [T,H] (fp32 store)
  gemm_bt<1><<<(T_TOK / 128) * (H_DIM / 128), 256, 0, stream>>>(
      hs, wsdn_bf, out, nullptr, T_TOK, H_DIM, IS_DIM,
      nullptr, nullptr, nullptr, nullptr);
  // routed up: gathered x rows x w_up[e]^T -> h_pairs (relu^2 * w, bf16)
  gemm_bt<2><<<E_NUM * MAXMT * (I_DIM / 128), 256, 0, stream>>>(
      x_bf, wup_bf, nullptr, hp, T_TOK, I_DIM, H_DIM,
      counts, offsets, tok_list, w_list);
  // routed down: h_pairs x w_down[e]^T -> atomicAdd out [T,H]
  gemm_bt<3><<<E_NUM * MAXMT * (H_DIM / 128), 256, 0, stream>>>(
      hp, wdn_bf, out, nullptr, T_TOK, H_DIM, I_DIM,
      counts, offsets, tok_list, w_list);
}

// Round 2
// 302.212 us; speedup vs baseline: 1.4362x; 1.4362x over previous
//
#include <hip/hip_runtime.h>
#include <stdint.h>

#define T_TOK 4096
#define H_DIM 1024
#define E_NUM 16
#define I_DIM 512
#define IS_DIM 2048
#define TOPK 4
#define NGRP 4
#define GSZ 4
#define MAXMT 32

typedef unsigned short u16;
typedef __attribute__((ext_vector_type(8))) short short8;
typedef __attribute__((ext_vector_type(4))) float f32x4;

__device__ __forceinline__ void gload16(const void* g, void* l) {
  __builtin_amdgcn_global_load_lds(
      (const __attribute__((address_space(1))) void*)g,
      (__attribute__((address_space(3))) void*)l, 16, 0, 0);
}

__device__ __forceinline__ u16 f2bf(float f) {
  union { float f; uint32_t u; } v; v.f = f;
  uint32_t u = v.u;
  uint32_t r = (u + 0x7fffu + ((u >> 16) & 1u)) >> 16;
  return (u16)r;
}

// ---------------- fp32 -> bf16 conversion ----------------
__global__ __launch_bounds__(256) void cvt_bf16_kernel(const float* __restrict__ in,
                                                       u16* __restrict__ out, int n4) {
  int i = blockIdx.x * 256 + threadIdx.x;
  if (i >= n4) return;
  float4 v = reinterpret_cast<const float4*>(in)[i];
  ushort4 o;
  o.x = f2bf(v.x); o.y = f2bf(v.y); o.z = f2bf(v.z); o.w = f2bf(v.w);
  reinterpret_cast<ushort4*>(out)[i] = o;
}

// ---------------- routing: per-token top-4 (no atomics) ----------------
__global__ __launch_bounds__(256) void route_kernel(
    const float* __restrict__ x, const float* __restrict__ rw,
    const float* __restrict__ bias, int* __restrict__ tidx_out,
    float* __restrict__ tw_out) {
  const int wave = threadIdx.x >> 6;
  const int lane = threadIdx.x & 63;
  const int t = blockIdx.x * 4 + wave;

  const float4* xr = reinterpret_cast<const float4*>(x + (size_t)t * H_DIM);
  const float4* rw4 = reinterpret_cast<const float4*>(rw);
  float4 xv[4];
#pragma unroll
  for (int j = 0; j < 4; ++j) xv[j] = xr[lane + j * 64];

  double acc[E_NUM];
#pragma unroll
  for (int e = 0; e < E_NUM; ++e) {
    double a = 0.0;
#pragma unroll
    for (int j = 0; j < 4; ++j) {
      float4 w = rw4[e * 256 + lane + j * 64];
      a += (double)xv[j].x * (double)w.x;
      a += (double)xv[j].y * (double)w.y;
      a += (double)xv[j].z * (double)w.z;
      a += (double)xv[j].w * (double)w.w;
    }
    acc[e] = a;
  }
#pragma unroll
  for (int e = 0; e < E_NUM; ++e) {
#pragma unroll
    for (int off = 32; off; off >>= 1) acc[e] += __shfl_xor(acc[e], off);
  }
  if (lane == 0) {
    float scores[E_NUM], sfc[E_NUM];
#pragma unroll
    for (int e = 0; e < E_NUM; ++e) {
      scores[e] = 1.0f / (1.0f + expf((float)(-acc[e])));
      sfc[e] = scores[e] + bias[e];
    }
    float gs[NGRP];
#pragma unroll
    for (int g = 0; g < NGRP; ++g) {
      float m1 = -1e30f, m2 = -1e30f;
#pragma unroll
      for (int j = 0; j < GSZ; ++j) {
        float v = sfc[g * GSZ + j];
        if (v > m1) { m2 = m1; m1 = v; } else if (v > m2) { m2 = v; }
      }
      gs[g] = m1 + m2;
    }
    int g1 = 0;
    for (int g = 1; g < NGRP; ++g) if (gs[g] > gs[g1]) g1 = g;
    int g2 = -1;
    for (int g = 0; g < NGRP; ++g) {
      if (g == g1) continue;
      if (g2 < 0 || gs[g] > gs[g2]) g2 = g;
    }
    float masked[E_NUM];
#pragma unroll
    for (int e = 0; e < E_NUM; ++e) {
      int g = e / GSZ;
      masked[e] = (g == g1 || g == g2) ? sfc[e] : 0.0f;
    }
    int tidx[TOPK]; float tw[TOPK];
#pragma unroll
    for (int k = 0; k < TOPK; ++k) {
      int best = 0; float bv = masked[0];
      for (int e = 1; e < E_NUM; ++e)
        if (masked[e] > bv) { bv = masked[e]; best = e; }
      tidx[k] = best; tw[k] = scores[best]; masked[best] = -1e30f;
    }
    float s = tw[0] + tw[1] + tw[2] + tw[3] + 1e-20f;
#pragma unroll
    for (int k = 0; k < TOPK; ++k) {
      tidx_out[t * TOPK + k] = tidx[k];
      tw_out[t * TOPK + k] = tw[k] / s * 2.5f;
    }
  }
}

// ---------------- scatter: per-expert compaction (no atomics) ----------------
__global__ __launch_bounds__(256) void scatter_kernel(
    const int* __restrict__ tidx, const float* __restrict__ tw,
    int* __restrict__ counts, int* __restrict__ tok_list,
    float* __restrict__ w_list) {
  const int e = blockIdx.x;
  const int tid = threadIdx.x;
  const int lane = tid & 63;
  const int w = tid >> 6;
  __shared__ int wsum[4];
  __shared__ int base;
  if (tid == 0) base = 0;
  __syncthreads();
  for (int c = 0; c < (T_TOK * TOPK) / 256; ++c) {
    int i = c * 256 + tid;
    bool p = (tidx[i] == e);
    unsigned long long b = __ballot(p);
    int pre = __popcll(b & ((1ull << lane) - 1ull));
    if (lane == 0) wsum[w] = __popcll(b);
    __syncthreads();
    int woff = base;
    for (int j = 0; j < w; ++j) woff += wsum[j];
    int tot = wsum[0] + wsum[1] + wsum[2] + wsum[3];
    if (p) {
      int pos = woff + pre;
      tok_list[e * T_TOK + pos] = i >> 2;
      w_list[e * T_TOK + pos] = tw[i];
    }
    __syncthreads();
    if (tid == 0) base += tot;
    __syncthreads();
  }
  if (tid == 0) counts[e] = base;
}

__global__ void prefix_kernel(const int* __restrict__ counts, int* __restrict__ offsets) {
  if (threadIdx.x == 0) {
    int s = 0;
    for (int e = 0; e < E_NUM; ++e) { offsets[e] = s; s += counts[e]; }
    offsets[E_NUM] = s;
  }
}

// ---------------- bf16 MFMA GEMM: C = A * B^T ----------------
// EPI 0: shared-up   : C=hs bf16, relu^2
// EPI 1: shared-down : C=out fp32 plain store
// EPI 2: routed-up   : A gathered by token list, C=h_pairs bf16, relu^2 * w
// EPI 3: routed-down : C scattered by token list, fp32 atomicAdd into out
template <int EPI>
__global__ __launch_bounds__(256) void gemm_bt(
    const u16* __restrict__ Abase, const u16* __restrict__ Bbase,
    float* __restrict__ Cf, u16* __restrict__ Cb,
    int M, int N, int K,
    const int* __restrict__ counts, const int* __restrict__ offsets,
    const int* __restrict__ tok_list, const float* __restrict__ w_list) {
  __shared__ __align__(16) u16 As[128 * 32];
  __shared__ __align__(16) u16 Bs[128 * 32];

  const int NT = N >> 7;
  int mt, nt, cnt = M, obase = 0;
  const int* toks = nullptr;
  const float* rww = nullptr;
  const u16* A = Abase;
  const u16* B = Bbase;

  if constexpr (EPI <= 1) {
    mt = blockIdx.x / NT;
    nt = blockIdx.x - mt * NT;
  } else {
    const int per_e = MAXMT * NT;
    int e = blockIdx.x / per_e;
    int r = blockIdx.x - e * per_e;
    mt = r / NT;
    nt = r - mt * NT;
    cnt = counts[e];
    if (mt * 128 >= cnt) return;
    obase = offsets[e];
    toks = tok_list + e * T_TOK;
    rww = w_list + e * T_TOK;
    if constexpr (EPI == 2) {
      B = Bbase + (size_t)e * (I_DIM * H_DIM);
    } else {
      A = Abase + (size_t)obase * I_DIM;
      B = Bbase + (size_t)e * (H_DIM * I_DIM);
    }
  }

  const int tid = threadIdx.x;
  const int srow = tid >> 2;
  const int skcol = (tid & 3) << 3;
  const u16* gA[2];
  const u16* gB[2];
#pragma unroll
  for (int p = 0; p < 2; ++p) {
    int row = srow + (p << 6);
    int am = mt * 128 + row;
    if constexpr (EPI == 2) {
      int tk = toks[(am < cnt) ? am : 0];
      gA[p] = Abase + (size_t)tk * H_DIM + skcol;
    } else if constexpr (EPI == 3) {
      int ar = (am < cnt) ? am : 0;
      gA[p] = A + (size_t)ar * K + skcol;
    } else {
      gA[p] = A + (size_t)am * K + skcol;
    }
    gB[p] = B + (size_t)(nt * 128 + row) * K + skcol;
  }

  const int wave = tid >> 6;
  const int lane = tid & 63;
  const int wrow = (wave >> 1) << 6;
  const int wcol = (wave & 1) << 6;
  const int frow = lane & 15;
  const int fk = (lane >> 4) << 3;

  f32x4 acc[4][4];
#pragma unroll
  for (int m = 0; m < 4; ++m)
#pragma unroll
    for (int n = 0; n < 4; ++n) acc[m][n] = (f32x4)0.0f;

  u16* asw = &As[tid << 3];
  u16* bsw = &Bs[tid << 3];
  const u16* ar0 = &As[(wrow + frow) * 32 + fk];
  const u16* br0 = &Bs[(wcol + frow) * 32 + fk];

  for (int k0 = 0; k0 < K; k0 += 32) {
#pragma unroll
    for (int p = 0; p < 2; ++p) {
      gload16(gA[p] + k0, asw + (p << 11));
      gload16(gB[p] + k0, bsw + (p << 11));
    }
    __syncthreads();
    short8 a[4], b[4];
#pragma unroll
    for (int m = 0; m < 4; ++m)
      a[m] = *reinterpret_cast<const short8*>(ar0 + (m << 4) * 32);
#pragma unroll
    for (int n = 0; n < 4; ++n)
      b[n] = *reinterpret_cast<const short8*>(br0 + (n << 4) * 32);
#pragma unroll
    for (int m = 0; m < 4; ++m)
#pragma unroll
      for (int n = 0; n < 4; ++n)
        acc[m][n] = __builtin_amdgcn_mfma_f32_16x16x32_bf16(a[m], b[n], acc[m][n], 0, 0, 0);
    __syncthreads();
  }

  const int rbase = (lane >> 4) << 2;
  const int cbase = lane & 15;
#pragma unroll
  for (int m = 0; m < 4; ++m) {
#pragma unroll
    for (int r = 0; r < 4; ++r) {
      int lr = wrow + (m << 4) + rbase + r;
      int grow = mt * 128 + lr;
      if (EPI >= 2 && grow >= cnt) continue;
      float wv = 1.0f;
      int orow = grow;
      if constexpr (EPI == 2) wv = rww[grow];
      if constexpr (EPI == 3) orow = toks[grow];
#pragma unroll
      for (int n = 0; n < 4; ++n) {
        int gc = nt * 128 + wcol + (n << 4) + cbase;
        float v = acc[m][n][r];
        if constexpr (EPI == 0) {
          float tpos = fmaxf(v, 0.0f);
          Cb[(size_t)grow * N + gc] = f2bf(tpos * tpos);
        } else if constexpr (EPI == 1) {
          Cf[(size_t)grow * N + gc] = v;
        } else if constexpr (EPI == 2) {
          float tpos = fmaxf(v, 0.0f);
          Cb[(size_t)(obase + grow) * I_DIM + gc] = f2bf(tpos * tpos * wv);
        } else {
          atomicAdd(&Cf[(size_t)orow * H_DIM + gc], v);
        }
      }
    }
  }
}

// ---------------- launch ----------------
extern "C" void kernel_launch(void* const* d_in, const int* in_sizes, int n_in,
                              void* d_out, int out_size, void* d_ws, size_t ws_size,
                              hipStream_t stream) {
  const float* x = (const float*)d_in[0];
  const float* rw = (const float*)d_in[1];
  const float* bias = (const float*)d_in[2];
  const float* w_up = (const float*)d_in[3];
  const float* w_down = (const float*)d_in[4];
  const float* ws_up = (const float*)d_in[5];
  const float* ws_down = (const float*)d_in[6];
  float* out = (float*)d_out;

  uint8_t* wsb = (uint8_t*)d_ws;
  size_t off = 0;
  auto alloc = [&](size_t bytes) {
    void* p = wsb + off;
    off += (bytes + 255) & ~(size_t)255;
    return p;
  };
  u16* x_bf = (u16*)alloc((size_t)T_TOK * H_DIM * 2);
  u16* wsup_bf = (u16*)alloc((size_t)IS_DIM * H_DIM * 2);
  u16* wsdn_bf = (u16*)alloc((size_t)H_DIM * IS_DIM * 2);
  u16* wup_bf = (u16*)alloc((size_t)E_NUM * I_DIM * H_DIM * 2);
  u16* wdn_bf = (u16*)alloc((size_t)E_NUM * H_DIM * I_DIM * 2);
  u16* hs = (u16*)alloc((size_t)T_TOK * IS_DIM * 2);
  u16* hp = (u16*)alloc((size_t)(T_TOK * TOPK + 128) * I_DIM * 2);
  int* counts = (int*)alloc(64);
  int* offsets = (int*)alloc(128);
  int* tok_list = (int*)alloc((size_t)E_NUM * T_TOK * 4);
  float* w_list = (float*)alloc((size_t)E_NUM * T_TOK * 4);
  int* tidx_buf = (int*)alloc((size_t)T_TOK * TOPK * 4);
  float* tw_buf = (float*)alloc((size_t)T_TOK * TOPK * 4);

  int n4;
  n4 = T_TOK * H_DIM / 4;
  cvt_bf16_kernel<<<(n4 + 255) / 256, 256, 0, stream>>>(x, x_bf, n4);
  n4 = IS_DIM * H_DIM / 4;
  cvt_bf16_kernel<<<(n4 + 255) / 256, 256, 0, stream>>>(ws_up, wsup_bf, n4);
  n4 = H_DIM * IS_DIM / 4;
  cvt_bf16_kernel<<<(n4 + 255) / 256, 256, 0, stream>>>(ws_down, wsdn_bf, n4);
  n4 = E_NUM * I_DIM * H_DIM / 4;
  cvt_bf16_kernel<<<(n4 + 255) / 256, 256, 0, stream>>>(w_up, wup_bf, n4);
  n4 = E_NUM * H_DIM * I_DIM / 4;
  cvt_bf16_kernel<<<(n4 + 255) / 256, 256, 0, stream>>>(w_down, wdn_bf, n4);

  route_kernel<<<T_TOK / 4, 256, 0, stream>>>(x, rw, bias, tidx_buf, tw_buf);
  scatter_kernel<<<E_NUM, 256, 0, stream>>>(tidx_buf, tw_buf, counts, tok_list, w_list);
  prefix_kernel<<<1, 64, 0, stream>>>(counts, offsets);

  // shared up: [T,H] x [IS,H]^T -> hs [T,IS] (relu^2, bf16)
  gemm_bt<0><<<(T_TOK / 128) * (IS_DIM / 128), 256, 0, stream>>>(
      x_bf, wsup_bf, nullptr, hs, T_TOK, IS_DIM, H_DIM,
      nullptr, nullptr, nullptr, nullptr);
  // shared down: [T,IS] x [H,IS]^T -> out [T,H] (fp32 store)
  gemm_bt<1><<<(T_TOK / 128) * (H_DIM / 128), 256, 0, stream>>>(
      hs, wsdn_bf, out, nullptr, T_TOK, H_DIM, IS_DIM,
      nullptr, nullptr, nullptr, nullptr);
  // routed up: gathered x rows x w_up[e]^T -> h_pairs (relu^2 * w, bf16)
  gemm_bt<2><<<E_NUM * MAXMT * (I_DIM / 128), 256, 0, stream>>>(
      x_bf, wup_bf, nullptr, hp, T_TOK, I_DIM, H_DIM,
      counts, offsets, tok_list, w_list);
  // routed down: h_pairs x w_down[e]^T -> atomicAdd out [T,H]
  gemm_bt<3><<<E_NUM * MAXMT * (H_DIM / 128), 256, 0, stream>>>(
      hp, wdn_bf, out, nullptr, T_TOK, H_DIM, I_DIM,
      counts, offsets, tok_list, w_list);
}

// Round 3
// 268.762 us; speedup vs baseline: 1.6149x; 1.1245x over previous
//
#include <hip/hip_runtime.h>
#include <stdint.h>

#define T_TOK 4096
#define H_DIM 1024
#define E_NUM 16
#define I_DIM 512
#define IS_DIM 2048
#define TOPK 4
#define NGRP 4
#define GSZ 4
#define MAXMT 32

typedef unsigned short u16;
typedef __attribute__((ext_vector_type(8))) short short8;
typedef __attribute__((ext_vector_type(4))) float f32x4;

__device__ __forceinline__ void gload16(const void* g, void* l) {
  __builtin_amdgcn_global_load_lds(
      (const __attribute__((address_space(1))) void*)g,
      (__attribute__((address_space(3))) void*)l, 16, 0, 0);
}

__device__ __forceinline__ u16 f2bf(float f) {
  union { float f; uint32_t u; } v; v.f = f;
  uint32_t u = v.u;
  uint32_t r = (u + 0x7fffu + ((u >> 16) & 1u)) >> 16;
  return (u16)r;
}

// ---------------- fp32 -> bf16 conversion ----------------
__global__ __launch_bounds__(256) void cvt_bf16_kernel(const float* __restrict__ in,
                                                       u16* __restrict__ out, int n4) {
  int i = blockIdx.x * 256 + threadIdx.x;
  if (i >= n4) return;
  float4 v = reinterpret_cast<const float4*>(in)[i];
  ushort4 o;
  o.x = f2bf(v.x); o.y = f2bf(v.y); o.z = f2bf(v.z); o.w = f2bf(v.w);
  reinterpret_cast<ushort4*>(out)[i] = o;
}

// ---------------- routing: per-token top-4 (no atomics) ----------------
__global__ __launch_bounds__(256) void route_kernel(
    const float* __restrict__ x, const float* __restrict__ rw,
    const float* __restrict__ bias, int* __restrict__ tidx_out,
    float* __restrict__ tw_out) {
  const int wave = threadIdx.x >> 6;
  const int lane = threadIdx.x & 63;
  const int t = blockIdx.x * 4 + wave;

  const float4* xr = reinterpret_cast<const float4*>(x + (size_t)t * H_DIM);
  const float4* rw4 = reinterpret_cast<const float4*>(rw);
  float4 xv[4];
#pragma unroll
  for (int j = 0; j < 4; ++j) xv[j] = xr[lane + j * 64];

  double acc[E_NUM];
#pragma unroll
  for (int e = 0; e < E_NUM; ++e) {
    double a = 0.0;
#pragma unroll
    for (int j = 0; j < 4; ++j) {
      float4 w = rw4[e * 256 + lane + j * 64];
      a += (double)xv[j].x * (double)w.x;
      a += (double)xv[j].y * (double)w.y;
      a += (double)xv[j].z * (double)w.z;
      a += (double)xv[j].w * (double)w.w;
    }
    acc[e] = a;
  }
#pragma unroll
  for (int e = 0; e < E_NUM; ++e) {
#pragma unroll
    for (int off = 32; off; off >>= 1) acc[e] += __shfl_xor(acc[e], off);
  }
  if (lane == 0) {
    float scores[E_NUM], sfc[E_NUM];
#pragma unroll
    for (int e = 0; e < E_NUM; ++e) {
      scores[e] = 1.0f / (1.0f + expf((float)(-acc[e])));
      sfc[e] = scores[e] + bias[e];
    }
    float gs[NGRP];
#pragma unroll
    for (int g = 0; g < NGRP; ++g) {
      float m1 = -1e30f, m2 = -1e30f;
#pragma unroll
      for (int j = 0; j < GSZ; ++j) {
        float v = sfc[g * GSZ + j];
        if (v > m1) { m2 = m1; m1 = v; } else if (v > m2) { m2 = v; }
      }
      gs[g] = m1 + m2;
    }
    int g1 = 0;
    for (int g = 1; g < NGRP; ++g) if (gs[g] > gs[g1]) g1 = g;
    int g2 = -1;
    for (int g = 0; g < NGRP; ++g) {
      if (g == g1) continue;
      if (g2 < 0 || gs[g] > gs[g2]) g2 = g;
    }
    float masked[E_NUM];
#pragma unroll
    for (int e = 0; e < E_NUM; ++e) {
      int g = e / GSZ;
      masked[e] = (g == g1 || g == g2) ? sfc[e] : 0.0f;
    }
    int tidx[TOPK]; float tw[TOPK];
#pragma unroll
    for (int k = 0; k < TOPK; ++k) {
      int best = 0; float bv = masked[0];
      for (int e = 1; e < E_NUM; ++e)
        if (masked[e] > bv) { bv = masked[e]; best = e; }
      tidx[k] = best; tw[k] = scores[best]; masked[best] = -1e30f;
    }
    float s = tw[0] + tw[1] + tw[2] + tw[3] + 1e-20f;
#pragma unroll
    for (int k = 0; k < TOPK; ++k) {
      tidx_out[t * TOPK + k] = tidx[k];
      tw_out[t * TOPK + k] = tw[k] / s * 2.5f;
    }
  }
}

// ---------------- count per expert (no atomics) ----------------
__global__ __launch_bounds__(256) void count_kernel(const int* __restrict__ tidx,
                                                    int* __restrict__ counts) {
  const int e = blockIdx.x;
  const int tid = threadIdx.x;
  const int lane = tid & 63;
  const int w = tid >> 6;
  int c = 0;
  for (int i = tid; i < T_TOK * TOPK; i += 256) c += (tidx[i] == e);
#pragma unroll
  for (int off = 32; off; off >>= 1) c += __shfl_xor(c, off);
  __shared__ int ws[4];
  if (lane == 0) ws[w] = c;
  __syncthreads();
  if (tid == 0) counts[e] = ws[0] + ws[1] + ws[2] + ws[3];
}

__global__ void prefix_kernel(const int* __restrict__ counts, int* __restrict__ offsets) {
  if (threadIdx.x == 0) {
    int s = 0;
    for (int e = 0; e < E_NUM; ++e) { offsets[e] = s; s += counts[e]; }
    offsets[E_NUM] = s;
  }
}

// ---------------- scatter: compact global lists + pos_map ----------------
__global__ __launch_bounds__(256) void scatter_kernel(
    const int* __restrict__ tidx, const float* __restrict__ tw,
    const int* __restrict__ offsets,
    int* __restrict__ tok_g, float* __restrict__ w_g, int* __restrict__ pos_map) {
  const int e = blockIdx.x;
  const int tid = threadIdx.x;
  const int lane = tid & 63;
  const int w = tid >> 6;
  __shared__ int wsum[4];
  __shared__ int base;
  if (tid == 0) base = offsets[e];
  __syncthreads();
  for (int c = 0; c < (T_TOK * TOPK) / 256; ++c) {
    int i = c * 256 + tid;
    bool p = (tidx[i] == e);
    unsigned long long b = __ballot(p);
    int pre = __popcll(b & ((1ull << lane) - 1ull));
    if (lane == 0) wsum[w] = __popcll(b);
    __syncthreads();
    int woff = base;
    for (int j = 0; j < w; ++j) woff += wsum[j];
    int tot = wsum[0] + wsum[1] + wsum[2] + wsum[3];
    if (p) {
      int pos = woff + pre;
      tok_g[pos] = i >> 2;
      w_g[pos] = tw[i];
      pos_map[i] = pos;
    }
    __syncthreads();
    if (tid == 0) base += tot;
    __syncthreads();
  }
}

// ---------------- bf16 MFMA GEMM: C = A * B^T  (BK=64, XOR-swizzled LDS) ----
// EPI 0: shared-up   : C=hs bf16, relu^2
// EPI 1: shared-down : out[t] = acc + sum_k Rd[pos_map[t*4+k]]  (fp32 store)
// EPI 2: routed-up   : A gathered via tok_g, C=hp bf16, relu^2 * w
// EPI 3: routed-down : C=Rd fp32 plain store at row obase+grow
template <int EPI>
__global__ __launch_bounds__(256) void gemm_bt(
    const u16* __restrict__ Abase, const u16* __restrict__ Bbase,
    float* __restrict__ Cf, u16* __restrict__ Cb,
    int M, int N, int K,
    const int* __restrict__ counts, const int* __restrict__ offsets,
    const int* __restrict__ tok_g, const float* __restrict__ w_g,
    const int* __restrict__ pos_map, const float* __restrict__ Rd) {
  __shared__ __align__(16) u16 As[128 * 64];
  __shared__ __align__(16) u16 Bs[128 * 64];

  const int NT = N >> 7;
  int mt, nt, cnt = M, obase = 0;
  const u16* A = Abase;
  const u16* B = Bbase;

  if constexpr (EPI <= 1) {
    mt = blockIdx.x / NT;
    nt = blockIdx.x - mt * NT;
  } else {
    const int per_e = MAXMT * NT;
    int e = blockIdx.x / per_e;
    int r = blockIdx.x - e * per_e;
    mt = r / NT;
    nt = r - mt * NT;
    cnt = counts[e];
    if (mt * 128 >= cnt) return;
    obase = offsets[e];
    if constexpr (EPI == 2) {
      B = Bbase + (size_t)e * (I_DIM * H_DIM);
    } else {
      A = Abase + (size_t)obase * I_DIM;
      B = Bbase + (size_t)e * (H_DIM * I_DIM);
    }
  }

  const int tid = threadIdx.x;
  // staging: thread -> (row = p*32 + tid/8, 16B-slot = tid%8), slot XOR (row&7)
  const int srow = tid >> 3;
  const int slot = tid & 7;
  const u16* gA[4];
  const u16* gB[4];
#pragma unroll
  for (int p = 0; p < 4; ++p) {
    int rloc = p * 32 + srow;
    int ks = ((slot ^ (rloc & 7)) << 3);
    int am = mt * 128 + rloc;
    if constexpr (EPI == 2) {
      int tk = tok_g[obase + ((am < cnt) ? am : 0)];
      gA[p] = Abase + (size_t)tk * H_DIM + ks;
    } else if constexpr (EPI == 3) {
      gA[p] = A + (size_t)((am < cnt) ? am : 0) * K + ks;
    } else {
      gA[p] = A + (size_t)am * K + ks;
    }
    gB[p] = B + (size_t)(nt * 128 + rloc) * K + ks;
  }

  const int wave = tid >> 6;
  const int lane = tid & 63;
  const int wrow = (wave >> 1) << 6;
  const int wcol = (wave & 1) << 6;
  const int frow = lane & 15;
  const int l4 = lane >> 4;
  const int rxor = frow & 7;

  f32x4 acc[4][4];
#pragma unroll
  for (int m = 0; m < 4; ++m)
#pragma unroll
    for (int n = 0; n < 4; ++n) acc[m][n] = (f32x4)0.0f;

  u16* lsd = &As[0] + (tid << 3);  // A/B share the per-thread linear slot shape
  const u16* arp = &As[(wrow + frow) << 6];
  const u16* brp = &Bs[(wcol + frow) << 6];
  const int soff0 = ((0 * 4 + l4) ^ rxor) << 3;
  const int soff1 = ((1 * 4 + l4) ^ rxor) << 3;

  for (int k0 = 0; k0 < K; k0 += 64) {
#pragma unroll
    for (int p = 0; p < 4; ++p)
      gload16(gA[p] + k0, &As[(p << 11)] + (tid << 3));
#pragma unroll
    for (int p = 0; p < 4; ++p)
      gload16(gB[p] + k0, &Bs[(p << 11)] + (tid << 3));
    __syncthreads();
    short8 a[4], b[4];
#pragma unroll
    for (int m = 0; m < 4; ++m)
      a[m] = *reinterpret_cast<const short8*>(arp + (m << 10) + soff0);
#pragma unroll
    for (int n = 0; n < 4; ++n)
      b[n] = *reinterpret_cast<const short8*>(brp + (n << 10) + soff0);
#pragma unroll
    for (int m = 0; m < 4; ++m)
#pragma unroll
      for (int n = 0; n < 4; ++n)
        acc[m][n] = __builtin_amdgcn_mfma_f32_16x16x32_bf16(a[m], b[n], acc[m][n], 0, 0, 0);
#pragma unroll
    for (int m = 0; m < 4; ++m)
      a[m] = *reinterpret_cast<const short8*>(arp + (m << 10) + soff1);
#pragma unroll
    for (int n = 0; n < 4; ++n)
      b[n] = *reinterpret_cast<const short8*>(brp + (n << 10) + soff1);
#pragma unroll
    for (int m = 0; m < 4; ++m)
#pragma unroll
      for (int n = 0; n < 4; ++n)
        acc[m][n] = __builtin_amdgcn_mfma_f32_16x16x32_bf16(a[m], b[n], acc[m][n], 0, 0, 0);
    __syncthreads();
  }

  const int rbase = (lane >> 4) << 2;
  const int cbase = lane & 15;
#pragma unroll
  for (int m = 0; m < 4; ++m) {
#pragma unroll
    for (int r = 0; r < 4; ++r) {
      int lr = wrow + (m << 4) + rbase + r;
      int grow = mt * 128 + lr;
      if (EPI >= 2 && grow >= cnt) continue;
      float wv = 1.0f;
      if constexpr (EPI == 2) wv = w_g[obase + grow];
      const int* pm = nullptr;
      if constexpr (EPI == 1) pm = pos_map + grow * TOPK;
#pragma unroll
      for (int n = 0; n < 4; ++n) {
        int gc = nt * 128 + wcol + (n << 4) + cbase;
        float v = acc[m][n][r];
        if constexpr (EPI == 0) {
          float tpos = fmaxf(v, 0.0f);
          Cb[(size_t)grow * N + gc] = f2bf(tpos * tpos);
        } else if constexpr (EPI == 1) {
          v += Rd[(size_t)pm[0] * H_DIM + gc];
          v += Rd[(size_t)pm[1] * H_DIM + gc];
          v += Rd[(size_t)pm[2] * H_DIM + gc];
          v += Rd[(size_t)pm[3] * H_DIM + gc];
          Cf[(size_t)grow * N + gc] = v;
        } else if constexpr (EPI == 2) {
          float tpos = fmaxf(v, 0.0f);
          Cb[(size_t)(obase + grow) * I_DIM + gc] = f2bf(tpos * tpos * wv);
        } else {
          Cf[(size_t)(obase + grow) * N + gc] = v;
        }
      }
    }
  }
}

// ---------------- launch ----------------
extern "C" void kernel_launch(void* const* d_in, const int* in_sizes, int n_in,
                              void* d_out, int out_size, void* d_ws, size_t ws_size,
                              hipStream_t stream) {
  const float* x = (const float*)d_in[0];
  const float* rw = (const float*)d_in[1];
  const float* bias = (const float*)d_in[2];
  const float* w_up = (const float*)d_in[3];
  const float* w_down = (const float*)d_in[4];
  const float* ws_up = (const float*)d_in[5];
  const float* ws_down = (const float*)d_in[6];
  float* out = (float*)d_out;

  uint8_t* wsb = (uint8_t*)d_ws;
  size_t off = 0;
  auto alloc = [&](size_t bytes) {
    void* p = wsb + off;
    off += (bytes + 255) & ~(size_t)255;
    return p;
  };
  u16* x_bf = (u16*)alloc((size_t)T_TOK * H_DIM * 2);
  u16* wsup_bf = (u16*)alloc((size_t)IS_DIM * H_DIM * 2);
  u16* wsdn_bf = (u16*)alloc((size_t)H_DIM * IS_DIM * 2);
  u16* wup_bf = (u16*)alloc((size_t)E_NUM * I_DIM * H_DIM * 2);
  u16* wdn_bf = (u16*)alloc((size_t)E_NUM * H_DIM * I_DIM * 2);
  u16* hs = (u16*)alloc((size_t)T_TOK * IS_DIM * 2);
  u16* hp = (u16*)alloc((size_t)(T_TOK * TOPK + 128) * I_DIM * 2);
  float* hp_down = (float*)alloc((size_t)(T_TOK * TOPK + 128) * H_DIM * 4);
  int* counts = (int*)alloc(64);
  int* offsets = (int*)alloc(128);
  int* tok_g = (int*)alloc((size_t)(T_TOK * TOPK) * 4);
  float* w_g = (float*)alloc((size_t)(T_TOK * TOPK) * 4);
  int* pos_map = (int*)alloc((size_t)(T_TOK * TOPK) * 4);
  int* tidx_buf = (int*)alloc((size_t)T_TOK * TOPK * 4);
  float* tw_buf = (float*)alloc((size_t)T_TOK * TOPK * 4);

  int n4;
  n4 = T_TOK * H_DIM / 4;
  cvt_bf16_kernel<<<(n4 + 255) / 256, 256, 0, stream>>>(x, x_bf, n4);
  n4 = IS_DIM * H_DIM / 4;
  cvt_bf16_kernel<<<(n4 + 255) / 256, 256, 0, stream>>>(ws_up, wsup_bf, n4);
  n4 = H_DIM * IS_DIM / 4;
  cvt_bf16_kernel<<<(n4 + 255) / 256, 256, 0, stream>>>(ws_down, wsdn_bf, n4);
  n4 = E_NUM * I_DIM * H_DIM / 4;
  cvt_bf16_kernel<<<(n4 + 255) / 256, 256, 0, stream>>>(w_up, wup_bf, n4);
  n4 = E_NUM * H_DIM * I_DIM / 4;
  cvt_bf16_kernel<<<(n4 + 255) / 256, 256, 0, stream>>>(w_down, wdn_bf, n4);

  route_kernel<<<T_TOK / 4, 256, 0, stream>>>(x, rw, bias, tidx_buf, tw_buf);
  count_kernel<<<E_NUM, 256, 0, stream>>>(tidx_buf, counts);
  prefix_kernel<<<1, 64, 0, stream>>>(counts, offsets);
  scatter_kernel<<<E_NUM, 256, 0, stream>>>(tidx_buf, tw_buf, offsets, tok_g, w_g, pos_map);

  // shared up: [T,H] x [IS,H]^T -> hs (relu^2, bf16)
  gemm_bt<0><<<(T_TOK / 128) * (IS_DIM / 128), 256, 0, stream>>>(
      x_bf, wsup_bf, nullptr, hs, T_TOK, IS_DIM, H_DIM,
      nullptr, nullptr, nullptr, nullptr, nullptr, nullptr);
  // routed up: gathered x rows x w_up[e]^T -> hp (relu^2 * w, bf16)
  gemm_bt<2><<<E_NUM * MAXMT * (I_DIM / 128), 256, 0, stream>>>(
      x_bf, wup_bf, nullptr, hp, T_TOK, I_DIM, H_DIM,
      counts, offsets, tok_g, w_g, nullptr, nullptr);
  // routed down: hp x w_down[e]^T -> hp_down fp32 (plain store)
  gemm_bt<3><<<E_NUM * MAXMT * (H_DIM / 128), 256, 0, stream>>>(
      hp, wdn_bf, hp_down, nullptr, T_TOK, H_DIM, I_DIM,
      counts, offsets, tok_g, w_g, nullptr, nullptr);
  // shared down + routed gather: hs x [H,IS]^T + sum_k hp_down -> out
  gemm_bt<1><<<(T_TOK / 128) * (H_DIM / 128), 256, 0, stream>>>(
      hs, wsdn_bf, out, nullptr, T_TOK, H_DIM, IS_DIM,
      nullptr, nullptr, nullptr, nullptr, pos_map, hp_down);
}

// Round 4
// 253.085 us; speedup vs baseline: 1.7150x; 1.0619x over previous
//
#include <hip/hip_runtime.h>
#include <stdint.h>

#define T_TOK 4096
#define H_DIM 1024
#define E_NUM 16
#define I_DIM 512
#define IS_DIM 2048
#define TOPK 4
#define NGRP 4
#define GSZ 4
#define MAXMT 32

typedef unsigned short u16;
typedef __attribute__((ext_vector_type(8))) short short8;
typedef __attribute__((ext_vector_type(4))) float f32x4;

__device__ __forceinline__ void gload16(const void* g, void* l) {
  __builtin_amdgcn_global_load_lds(
      (const __attribute__((address_space(1))) void*)g,
      (__attribute__((address_space(3))) void*)l, 16, 0, 0);
}

__device__ __forceinline__ u16 f2bf(float f) {
  union { float f; uint32_t u; } v; v.f = f;
  uint32_t u = v.u;
  uint32_t r = (u + 0x7fffu + ((u >> 16) & 1u)) >> 16;
  return (u16)r;
}

__device__ __forceinline__ float bf2f(u16 h) {
  union { uint32_t u; float f; } v; v.u = ((uint32_t)h) << 16;
  return v.f;
}

// ---------------- fp32 -> bf16 conversion ----------------
__global__ __launch_bounds__(256) void cvt_bf16_kernel(const float* __restrict__ in,
                                                       u16* __restrict__ out, int n4) {
  int i = blockIdx.x * 256 + threadIdx.x;
  if (i >= n4) return;
  float4 v = reinterpret_cast<const float4*>(in)[i];
  ushort4 o;
  o.x = f2bf(v.x); o.y = f2bf(v.y); o.z = f2bf(v.z); o.w = f2bf(v.w);
  reinterpret_cast<ushort4*>(out)[i] = o;
}

// ---------------- routing: per-token top-4 (no atomics) ----------------
__global__ __launch_bounds__(256) void route_kernel(
    const float* __restrict__ x, const float* __restrict__ rw,
    const float* __restrict__ bias, int* __restrict__ tidx_out,
    float* __restrict__ tw_out) {
  const int wave = threadIdx.x >> 6;
  const int lane = threadIdx.x & 63;
  const int t = blockIdx.x * 4 + wave;

  const float4* xr = reinterpret_cast<const float4*>(x + (size_t)t * H_DIM);
  const float4* rw4 = reinterpret_cast<const float4*>(rw);
  float4 xv[4];
#pragma unroll
  for (int j = 0; j < 4; ++j) xv[j] = xr[lane + j * 64];

  double acc[E_NUM];
#pragma unroll
  for (int e = 0; e < E_NUM; ++e) {
    double a = 0.0;
#pragma unroll
    for (int j = 0; j < 4; ++j) {
      float4 w = rw4[e * 256 + lane + j * 64];
      a += (double)xv[j].x * (double)w.x;
      a += (double)xv[j].y * (double)w.y;
      a += (double)xv[j].z * (double)w.z;
      a += (double)xv[j].w * (double)w.w;
    }
    acc[e] = a;
  }
#pragma unroll
  for (int e = 0; e < E_NUM; ++e) {
#pragma unroll
    for (int off = 32; off; off >>= 1) acc[e] += __shfl_xor(acc[e], off);
  }
  if (lane == 0) {
    float scores[E_NUM], sfc[E_NUM];
#pragma unroll
    for (int e = 0; e < E_NUM; ++e) {
      scores[e] = 1.0f / (1.0f + expf((float)(-acc[e])));
      sfc[e] = scores[e] + bias[e];
    }
    float gs[NGRP];
#pragma unroll
    for (int g = 0; g < NGRP; ++g) {
      float m1 = -1e30f, m2 = -1e30f;
#pragma unroll
      for (int j = 0; j < GSZ; ++j) {
        float v = sfc[g * GSZ + j];
        if (v > m1) { m2 = m1; m1 = v; } else if (v > m2) { m2 = v; }
      }
      gs[g] = m1 + m2;
    }
    int g1 = 0;
    for (int g = 1; g < NGRP; ++g) if (gs[g] > gs[g1]) g1 = g;
    int g2 = -1;
    for (int g = 0; g < NGRP; ++g) {
      if (g == g1) continue;
      if (g2 < 0 || gs[g] > gs[g2]) g2 = g;
    }
    float masked[E_NUM];
#pragma unroll
    for (int e = 0; e < E_NUM; ++e) {
      int g = e / GSZ;
      masked[e] = (g == g1 || g == g2) ? sfc[e] : 0.0f;
    }
    int tidx[TOPK]; float tw[TOPK];
#pragma unroll
    for (int k = 0; k < TOPK; ++k) {
      int best = 0; float bv = masked[0];
      for (int e = 1; e < E_NUM; ++e)
        if (masked[e] > bv) { bv = masked[e]; best = e; }
      tidx[k] = best; tw[k] = scores[best]; masked[best] = -1e30f;
    }
    float s = tw[0] + tw[1] + tw[2] + tw[3] + 1e-20f;
#pragma unroll
    for (int k = 0; k < TOPK; ++k) {
      tidx_out[t * TOPK + k] = tidx[k];
      tw_out[t * TOPK + k] = tw[k] / s * 2.5f;
    }
  }
}

// ---------------- count per expert (no atomics) ----------------
__global__ __launch_bounds__(256) void count_kernel(const int* __restrict__ tidx,
                                                    int* __restrict__ counts) {
  const int e = blockIdx.x;
  const int tid = threadIdx.x;
  const int lane = tid & 63;
  const int w = tid >> 6;
  int c = 0;
  for (int i = tid; i < T_TOK * TOPK; i += 256) c += (tidx[i] == e);
#pragma unroll
  for (int off = 32; off; off >>= 1) c += __shfl_xor(c, off);
  __shared__ int ws[4];
  if (lane == 0) ws[w] = c;
  __syncthreads();
  if (tid == 0) counts[e] = ws[0] + ws[1] + ws[2] + ws[3];
}

__global__ void prefix_kernel(const int* __restrict__ counts, int* __restrict__ offsets) {
  if (threadIdx.x == 0) {
    int s = 0;
    for (int e = 0; e < E_NUM; ++e) { offsets[e] = s; s += counts[e]; }
    offsets[E_NUM] = s;
  }
}

// ---------------- scatter: compact global lists + pos_map ----------------
__global__ __launch_bounds__(256) void scatter_kernel(
    const int* __restrict__ tidx, const float* __restrict__ tw,
    const int* __restrict__ offsets,
    int* __restrict__ tok_g, float* __restrict__ w_g, int* __restrict__ pos_map) {
  const int e = blockIdx.x;
  const int tid = threadIdx.x;
  const int lane = tid & 63;
  const int w = tid >> 6;
  __shared__ int wsum[4];
  __shared__ int base;
  if (tid == 0) base = offsets[e];
  __syncthreads();
  for (int c = 0; c < (T_TOK * TOPK) / 256; ++c) {
    int i = c * 256 + tid;
    bool p = (tidx[i] == e);
    unsigned long long b = __ballot(p);
    int pre = __popcll(b & ((1ull << lane) - 1ull));
    if (lane == 0) wsum[w] = __popcll(b);
    __syncthreads();
    int woff = base;
    for (int j = 0; j < w; ++j) woff += wsum[j];
    int tot = wsum[0] + wsum[1] + wsum[2] + wsum[3];
    if (p) {
      int pos = woff + pre;
      tok_g[pos] = i >> 2;
      w_g[pos] = tw[i];
      pos_map[i] = pos;
    }
    __syncthreads();
    if (tid == 0) base += tot;
    __syncthreads();
  }
}

// ---------- bf16 MFMA GEMM: C = A * B^T (BK=64, dbuf pipeline, 8 waves) ----
// EPI 0: shared-up   : C=hs bf16, relu^2
// EPI 1: shared-down : out[t] = acc + sum_k bf2f(Rd[pos_map[t*4+k]])
// EPI 2: routed-up   : A gathered via tok_g, C=hp bf16, relu^2 * w
// EPI 3: routed-down : C=Rd bf16 plain store at row obase+grow
template <int EPI>
__global__ __launch_bounds__(512, 4) void gemm_bt(
    const u16* __restrict__ Abase, const u16* __restrict__ Bbase,
    float* __restrict__ Cf, u16* __restrict__ Cb,
    int M, int N, int K,
    const int* __restrict__ counts, const int* __restrict__ offsets,
    const int* __restrict__ tok_g, const float* __restrict__ w_g,
    const int* __restrict__ pos_map, const u16* __restrict__ Rd) {
  __shared__ __align__(16) u16 As[2][128 * 64];
  __shared__ __align__(16) u16 Bs[2][128 * 64];

  const int NT = N >> 7;
  int mt, nt, cnt = M, obase = 0;
  const u16* A = Abase;
  const u16* B = Bbase;

  if constexpr (EPI <= 1) {
    mt = blockIdx.x / NT;
    nt = blockIdx.x - mt * NT;
  } else {
    const int per_e = MAXMT * NT;
    int e = blockIdx.x / per_e;
    int r = blockIdx.x - e * per_e;
    mt = r / NT;
    nt = r - mt * NT;
    cnt = counts[e];
    if (mt * 128 >= cnt) return;
    obase = offsets[e];
    if constexpr (EPI == 2) {
      B = Bbase + (size_t)e * (I_DIM * H_DIM);
    } else {
      A = Abase + (size_t)obase * I_DIM;
      B = Bbase + (size_t)e * (H_DIM * I_DIM);
    }
  }

  const int tid = threadIdx.x;
  // staging: pass p covers rows p*64..p*64+63; row = p*64 + tid/8, slot = tid%8
  // global 16B-slot = slot ^ (row&7); LDS dest linear (tid*16B within pass)
  const int srow = tid >> 3;
  const int slot = tid & 7;
  const u16* gA[2];
  const u16* gB[2];
#pragma unroll
  for (int p = 0; p < 2; ++p) {
    int rloc = p * 64 + srow;
    int ks = ((slot ^ (rloc & 7)) << 3);
    int am = mt * 128 + rloc;
    if constexpr (EPI == 2) {
      int tk = tok_g[obase + ((am < cnt) ? am : 0)];
      gA[p] = Abase + (size_t)tk * H_DIM + ks;
    } else if constexpr (EPI == 3) {
      gA[p] = A + (size_t)((am < cnt) ? am : 0) * K + ks;
    } else {
      gA[p] = A + (size_t)am * K + ks;
    }
    gB[p] = B + (size_t)(nt * 128 + rloc) * K + ks;
  }

  const int wave = tid >> 6;
  const int lane = tid & 63;
  const int wr = wave >> 2;      // 0..1 : row-block of 64
  const int wc = wave & 3;       // 0..3 : col-block of 32
  const int frow = lane & 15;
  const int l4 = lane >> 4;

  // fragment LDS offsets (u16 units), swizzle-consistent read
  int a_off[4][2], b_off[2][2];
#pragma unroll
  for (int m = 0; m < 4; ++m) {
    int row = wr * 64 + m * 16 + frow;
#pragma unroll
    for (int kk = 0; kk < 2; ++kk)
      a_off[m][kk] = (row << 6) + ((((kk << 2) + l4) ^ (row & 7)) << 3);
  }
#pragma unroll
  for (int n = 0; n < 2; ++n) {
    int row = wc * 32 + n * 16 + frow;
#pragma unroll
    for (int kk = 0; kk < 2; ++kk)
      b_off[n][kk] = (row << 6) + ((((kk << 2) + l4) ^ (row & 7)) << 3);
  }

  f32x4 acc[4][2];
#pragma unroll
  for (int m = 0; m < 4; ++m)
#pragma unroll
    for (int n = 0; n < 2; ++n) acc[m][n] = (f32x4)0.0f;

  const int dst = tid << 3;  // u16 offset within pass
  auto stage = [&](int k0, int c) {
#pragma unroll
    for (int p = 0; p < 2; ++p)
      gload16(gA[p] + k0, &As[c][(p << 12) + dst]);
#pragma unroll
    for (int p = 0; p < 2; ++p)
      gload16(gB[p] + k0, &Bs[c][(p << 12) + dst]);
  };

  const int KT = K >> 6;
  stage(0, 0);
  int cur = 0;
  for (int kt = 0; kt < KT; ++kt) {
    __syncthreads();  // drains vmcnt(0): stage of cur complete, prev reads done
    if (kt + 1 < KT) stage((kt + 1) << 6, cur ^ 1);
#pragma unroll
    for (int kk = 0; kk < 2; ++kk) {
      short8 a[4], b[2];
#pragma unroll
      for (int m = 0; m < 4; ++m)
        a[m] = *reinterpret_cast<const short8*>(&As[cur][a_off[m][kk]]);
#pragma unroll
      for (int n = 0; n < 2; ++n)
        b[n] = *reinterpret_cast<const short8*>(&Bs[cur][b_off[n][kk]]);
#pragma unroll
      for (int m = 0; m < 4; ++m)
#pragma unroll
        for (int n = 0; n < 2; ++n)
          acc[m][n] = __builtin_amdgcn_mfma_f32_16x16x32_bf16(a[m], b[n], acc[m][n], 0, 0, 0);
    }
    cur ^= 1;
  }

  const int rbase = l4 << 2;
  const int cbase = frow;
#pragma unroll
  for (int m = 0; m < 4; ++m) {
#pragma unroll
    for (int r = 0; r < 4; ++r) {
      int lr = wr * 64 + (m << 4) + rbase + r;
      int grow = mt * 128 + lr;
      if (EPI >= 2 && grow >= cnt) continue;
      float wv = 1.0f;
      if constexpr (EPI == 2) wv = w_g[obase + grow];
      const int* pm = nullptr;
      if constexpr (EPI == 1) pm = pos_map + grow * TOPK;
#pragma unroll
      for (int n = 0; n < 2; ++n) {
        int gc = nt * 128 + wc * 32 + (n << 4) + cbase;
        float v = acc[m][n][r];
        if constexpr (EPI == 0) {
          float tpos = fmaxf(v, 0.0f);
          Cb[(size_t)grow * N + gc] = f2bf(tpos * tpos);
        } else if constexpr (EPI == 1) {
          v += bf2f(Rd[(size_t)pm[0] * H_DIM + gc]);
          v += bf2f(Rd[(size_t)pm[1] * H_DIM + gc]);
          v += bf2f(Rd[(size_t)pm[2] * H_DIM + gc]);
          v += bf2f(Rd[(size_t)pm[3] * H_DIM + gc]);
          Cf[(size_t)grow * N + gc] = v;
        } else if constexpr (EPI == 2) {
          float tpos = fmaxf(v, 0.0f);
          Cb[(size_t)(obase + grow) * I_DIM + gc] = f2bf(tpos * tpos * wv);
        } else {
          Cb[(size_t)(obase + grow) * N + gc] = f2bf(v);
        }
      }
    }
  }
}

// ---------------- launch ----------------
extern "C" void kernel_launch(void* const* d_in, const int* in_sizes, int n_in,
                              void* d_out, int out_size, void* d_ws, size_t ws_size,
                              hipStream_t stream) {
  const float* x = (const float*)d_in[0];
  const float* rw = (const float*)d_in[1];
  const float* bias = (const float*)d_in[2];
  const float* w_up = (const float*)d_in[3];
  const float* w_down = (const float*)d_in[4];
  const float* ws_up = (const float*)d_in[5];
  const float* ws_down = (const float*)d_in[6];
  float* out = (float*)d_out;

  uint8_t* wsb = (uint8_t*)d_ws;
  size_t off = 0;
  auto alloc = [&](size_t bytes) {
    void* p = wsb + off;
    off += (bytes + 255) & ~(size_t)255;
    return p;
  };
  u16* x_bf = (u16*)alloc((size_t)T_TOK * H_DIM * 2);
  u16* wsup_bf = (u16*)alloc((size_t)IS_DIM * H_DIM * 2);
  u16* wsdn_bf = (u16*)alloc((size_t)H_DIM * IS_DIM * 2);
  u16* wup_bf = (u16*)alloc((size_t)E_NUM * I_DIM * H_DIM * 2);
  u16* wdn_bf = (u16*)alloc((size_t)E_NUM * H_DIM * I_DIM * 2);
  u16* hs = (u16*)alloc((size_t)T_TOK * IS_DIM * 2);
  u16* hp = (u16*)alloc((size_t)(T_TOK * TOPK + 128) * I_DIM * 2);
  u16* hp_down = (u16*)alloc((size_t)(T_TOK * TOPK + 128) * H_DIM * 2);
  int* counts = (int*)alloc(64);
  int* offsets = (int*)alloc(128);
  int* tok_g = (int*)alloc((size_t)(T_TOK * TOPK) * 4);
  float* w_g = (float*)alloc((size_t)(T_TOK * TOPK) * 4);
  int* pos_map = (int*)alloc((size_t)(T_TOK * TOPK) * 4);
  int* tidx_buf = (int*)alloc((size_t)T_TOK * TOPK * 4);
  float* tw_buf = (float*)alloc((size_t)T_TOK * TOPK * 4);

  int n4;
  n4 = T_TOK * H_DIM / 4;
  cvt_bf16_kernel<<<(n4 + 255) / 256, 256, 0, stream>>>(x, x_bf, n4);
  n4 = IS_DIM * H_DIM / 4;
  cvt_bf16_kernel<<<(n4 + 255) / 256, 256, 0, stream>>>(ws_up, wsup_bf, n4);
  n4 = H_DIM * IS_DIM / 4;
  cvt_bf16_kernel<<<(n4 + 255) / 256, 256, 0, stream>>>(ws_down, wsdn_bf, n4);
  n4 = E_NUM * I_DIM * H_DIM / 4;
  cvt_bf16_kernel<<<(n4 + 255) / 256, 256, 0, stream>>>(w_up, wup_bf, n4);
  n4 = E_NUM * H_DIM * I_DIM / 4;
  cvt_bf16_kernel<<<(n4 + 255) / 256, 256, 0, stream>>>(w_down, wdn_bf, n4);

  route_kernel<<<T_TOK / 4, 256, 0, stream>>>(x, rw, bias, tidx_buf, tw_buf);
  count_kernel<<<E_NUM, 256, 0, stream>>>(tidx_buf, counts);
  prefix_kernel<<<1, 64, 0, stream>>>(counts, offsets);
  scatter_kernel<<<E_NUM, 256, 0, stream>>>(tidx_buf, tw_buf, offsets, tok_g, w_g, pos_map);

  // shared up: [T,H] x [IS,H]^T -> hs (relu^2, bf16)
  gemm_bt<0><<<(T_TOK / 128) * (IS_DIM / 128), 512, 0, stream>>>(
      x_bf, wsup_bf, nullptr, hs, T_TOK, IS_DIM, H_DIM,
      nullptr, nullptr, nullptr, nullptr, nullptr, nullptr);
  // routed up: gathered x rows x w_up[e]^T -> hp (relu^2 * w, bf16)
  gemm_bt<2><<<E_NUM * MAXMT * (I_DIM / 128), 512, 0, stream>>>(
      x_bf, wup_bf, nullptr, hp, T_TOK, I_DIM, H_DIM,
      counts, offsets, tok_g, w_g, nullptr, nullptr);
  // routed down: hp x w_down[e]^T -> hp_down bf16 (plain store)
  gemm_bt<3><<<E_NUM * MAXMT * (H_DIM / 128), 512, 0, stream>>>(
      hp, wdn_bf, nullptr, hp_down, T_TOK, H_DIM, I_DIM,
      counts, offsets, tok_g, w_g, nullptr, nullptr);
  // shared down + routed gather: hs x [H,IS]^T + sum_k hp_down -> out
  gemm_bt<1><<<(T_TOK / 128) * (H_DIM / 128), 512, 0, stream>>>(
      hs, wsdn_bf, out, nullptr, T_TOK, H_DIM, IS_DIM,
      nullptr, nullptr, nullptr, nullptr, pos_map, hp_down);
}

// Round 5
// 208.080 us; speedup vs baseline: 2.0859x; 1.2163x over previous
//
#include <hip/hip_runtime.h>
#include <stdint.h>

#define T_TOK 4096
#define H_DIM 1024
#define E_NUM 16
#define I_DIM 512
#define IS_DIM 2048
#define TOPK 4
#define NGRP 4
#define GSZ 4
#define MAXMT 32
#define NCHUNK 64  // (T_TOK*TOPK)/256

typedef unsigned short u16;
typedef __attribute__((ext_vector_type(8))) short short8;
typedef __attribute__((ext_vector_type(4))) float f32x4;

__device__ __forceinline__ void gload16(const void* g, void* l) {
  __builtin_amdgcn_global_load_lds(
      (const __attribute__((address_space(1))) void*)g,
      (__attribute__((address_space(3))) void*)l, 16, 0, 0);
}

__device__ __forceinline__ u16 f2bf(float f) {
  union { float f; uint32_t u; } v; v.f = f;
  uint32_t u = v.u;
  uint32_t r = (u + 0x7fffu + ((u >> 16) & 1u)) >> 16;
  return (u16)r;
}

__device__ __forceinline__ float bf2f(u16 h) {
  union { uint32_t u; float f; } v; v.u = ((uint32_t)h) << 16;
  return v.f;
}

// ---------------- fp32 -> bf16 conversion ----------------
__global__ __launch_bounds__(256) void cvt_bf16_kernel(const float* __restrict__ in,
                                                       u16* __restrict__ out, int n4) {
  int i = blockIdx.x * 256 + threadIdx.x;
  if (i >= n4) return;
  float4 v = reinterpret_cast<const float4*>(in)[i];
  ushort4 o;
  o.x = f2bf(v.x); o.y = f2bf(v.y); o.z = f2bf(v.z); o.w = f2bf(v.w);
  reinterpret_cast<ushort4*>(out)[i] = o;
}

// ---------------- routing: per-token top-4 (no atomics) ----------------
__global__ __launch_bounds__(256) void route_kernel(
    const float* __restrict__ x, const float* __restrict__ rw,
    const float* __restrict__ bias, int* __restrict__ tidx_out,
    float* __restrict__ tw_out) {
  const int wave = threadIdx.x >> 6;
  const int lane = threadIdx.x & 63;
  const int t = blockIdx.x * 4 + wave;

  const float4* xr = reinterpret_cast<const float4*>(x + (size_t)t * H_DIM);
  const float4* rw4 = reinterpret_cast<const float4*>(rw);
  float4 xv[4];
#pragma unroll
  for (int j = 0; j < 4; ++j) xv[j] = xr[lane + j * 64];

  double acc[E_NUM];
#pragma unroll
  for (int e = 0; e < E_NUM; ++e) {
    double a = 0.0;
#pragma unroll
    for (int j = 0; j < 4; ++j) {
      float4 w = rw4[e * 256 + lane + j * 64];
      a += (double)xv[j].x * (double)w.x;
      a += (double)xv[j].y * (double)w.y;
      a += (double)xv[j].z * (double)w.z;
      a += (double)xv[j].w * (double)w.w;
    }
    acc[e] = a;
  }
#pragma unroll
  for (int e = 0; e < E_NUM; ++e) {
#pragma unroll
    for (int off = 32; off; off >>= 1) acc[e] += __shfl_xor(acc[e], off);
  }
  if (lane == 0) {
    float scores[E_NUM], sfc[E_NUM];
#pragma unroll
    for (int e = 0; e < E_NUM; ++e) {
      scores[e] = 1.0f / (1.0f + expf((float)(-acc[e])));
      sfc[e] = scores[e] + bias[e];
    }
    float gs[NGRP];
#pragma unroll
    for (int g = 0; g < NGRP; ++g) {
      float m1 = -1e30f, m2 = -1e30f;
#pragma unroll
      for (int j = 0; j < GSZ; ++j) {
        float v = sfc[g * GSZ + j];
        if (v > m1) { m2 = m1; m1 = v; } else if (v > m2) { m2 = v; }
      }
      gs[g] = m1 + m2;
    }
    int g1 = 0;
    for (int g = 1; g < NGRP; ++g) if (gs[g] > gs[g1]) g1 = g;
    int g2 = -1;
    for (int g = 0; g < NGRP; ++g) {
      if (g == g1) continue;
      if (g2 < 0 || gs[g] > gs[g2]) g2 = g;
    }
    float masked[E_NUM];
#pragma unroll
    for (int e = 0; e < E_NUM; ++e) {
      int g = e / GSZ;
      masked[e] = (g == g1 || g == g2) ? sfc[e] : 0.0f;
    }
    int tidx[TOPK]; float tw[TOPK];
#pragma unroll
    for (int k = 0; k < TOPK; ++k) {
      int best = 0; float bv = masked[0];
      for (int e = 1; e < E_NUM; ++e)
        if (masked[e] > bv) { bv = masked[e]; best = e; }
      tidx[k] = best; tw[k] = scores[best]; masked[best] = -1e30f;
    }
    float s = tw[0] + tw[1] + tw[2] + tw[3] + 1e-20f;
#pragma unroll
    for (int k = 0; k < TOPK; ++k) {
      tidx_out[t * TOPK + k] = tidx[k];
      tw_out[t * TOPK + k] = tw[k] / s * 2.5f;
    }
  }
}

// ---------------- chunk histogram (64 blocks, one barrier) ----------------
__global__ __launch_bounds__(256) void hist_kernel(const int* __restrict__ tidx,
                                                   int* __restrict__ partial) {
  const int c = blockIdx.x;
  const int tid = threadIdx.x;
  const int lane = tid & 63;
  const int w = tid >> 6;
  __shared__ int h[4][E_NUM];
  const int e = tidx[c * 256 + tid];
#pragma unroll
  for (int ee = 0; ee < E_NUM; ++ee) {
    unsigned long long b = __ballot(e == ee);
    if (lane == 0) h[w][ee] = __popcll(b);
  }
  __syncthreads();
  if (tid < E_NUM)
    partial[c * E_NUM + tid] = h[0][tid] + h[1][tid] + h[2][tid] + h[3][tid];
}

// ------- per-expert chunk bases + expert offsets (1 block) -------
__global__ __launch_bounds__(256) void prefix2_kernel(
    const int* __restrict__ partial, int* __restrict__ chunk_base,
    int* __restrict__ counts, int* __restrict__ offsets) {
  __shared__ int tot[E_NUM];
  __shared__ int offs[E_NUM];
  const int tid = threadIdx.x;
  if (tid < E_NUM) {
    int run = 0;
    for (int c = 0; c < NCHUNK; ++c) {
      chunk_base[c * E_NUM + tid] = run;
      run += partial[c * E_NUM + tid];
    }
    tot[tid] = run;
    counts[tid] = run;
  }
  __syncthreads();
  if (tid == 0) {
    int s = 0;
    for (int e = 0; e < E_NUM; ++e) { offs[e] = s; offsets[e] = s; s += tot[e]; }
    offsets[E_NUM] = s;
  }
  __syncthreads();
  for (int i = tid; i < NCHUNK * E_NUM; i += 256)
    chunk_base[i] += offs[i & 15];
}

// ---------------- scatter (64 blocks, one barrier) ----------------
__global__ __launch_bounds__(256) void scatter2_kernel(
    const int* __restrict__ tidx, const float* __restrict__ tw,
    const int* __restrict__ chunk_base,
    int* __restrict__ tok_g, float* __restrict__ w_g, int* __restrict__ pos_map) {
  const int c = blockIdx.x;
  const int tid = threadIdx.x;
  const int lane = tid & 63;
  const int w = tid >> 6;
  __shared__ int h[4][E_NUM];
  const int i = c * 256 + tid;
  const int e = tidx[i];
  int pre = 0;
#pragma unroll
  for (int ee = 0; ee < E_NUM; ++ee) {
    unsigned long long b = __ballot(e == ee);
    if (lane == 0) h[w][ee] = __popcll(b);
    if (ee == e) pre = __popcll(b & ((1ull << lane) - 1ull));
  }
  __syncthreads();
  int rank = pre;
  for (int ww = 0; ww < w; ++ww) rank += h[ww][e];
  const int pos = chunk_base[c * E_NUM + e] + rank;
  tok_g[pos] = i >> 2;
  w_g[pos] = tw[i];
  pos_map[i] = pos;
}

// ---------- bf16 MFMA GEMM: C = A * B^T (BK=64, dbuf pipeline, 8 waves) ----
// EPI 0: shared-up   : C=hs bf16, relu^2
// EPI 1: shared-down : out[t] = acc + sum_k bf2f(Rd[pos_map[t*4+k]])
// EPI 2: routed-up   : A gathered via tok_g, C=hp bf16, relu^2 * w
// EPI 3: routed-down : C=Rd bf16 plain store at row obase+grow
template <int EPI>
__global__ __launch_bounds__(512, 4) void gemm_bt(
    const u16* __restrict__ Abase, const u16* __restrict__ Bbase,
    float* __restrict__ Cf, u16* __restrict__ Cb,
    int M, int N, int K,
    const int* __restrict__ counts, const int* __restrict__ offsets,
    const int* __restrict__ tok_g, const float* __restrict__ w_g,
    const int* __restrict__ pos_map, const u16* __restrict__ Rd) {
  __shared__ __align__(16) u16 As[2][128 * 64];
  __shared__ __align__(16) u16 Bs[2][128 * 64];

  const int NT = N >> 7;
  int mt, nt, cnt = M, obase = 0;
  const u16* A = Abase;
  const u16* B = Bbase;

  if constexpr (EPI <= 1) {
    mt = blockIdx.x / NT;
    nt = blockIdx.x - mt * NT;
  } else {
    const int per_e = MAXMT * NT;
    int e = blockIdx.x / per_e;
    int r = blockIdx.x - e * per_e;
    mt = r / NT;
    nt = r - mt * NT;
    cnt = counts[e];
    if (mt * 128 >= cnt) return;
    obase = offsets[e];
    if constexpr (EPI == 2) {
      B = Bbase + (size_t)e * (I_DIM * H_DIM);
    } else {
      A = Abase + (size_t)obase * I_DIM;
      B = Bbase + (size_t)e * (H_DIM * I_DIM);
    }
  }

  const int tid = threadIdx.x;
  const int srow = tid >> 3;
  const int slot = tid & 7;
  const u16* gA[2];
  const u16* gB[2];
#pragma unroll
  for (int p = 0; p < 2; ++p) {
    int rloc = p * 64 + srow;
    int ks = ((slot ^ (rloc & 7)) << 3);
    int am = mt * 128 + rloc;
    if constexpr (EPI == 2) {
      int tk = tok_g[obase + ((am < cnt) ? am : 0)];
      gA[p] = Abase + (size_t)tk * H_DIM + ks;
    } else if constexpr (EPI == 3) {
      gA[p] = A + (size_t)((am < cnt) ? am : 0) * K + ks;
    } else {
      gA[p] = A + (size_t)am * K + ks;
    }
    gB[p] = B + (size_t)(nt * 128 + rloc) * K + ks;
  }

  const int wave = tid >> 6;
  const int lane = tid & 63;
  const int wr = wave >> 2;
  const int wc = wave & 3;
  const int frow = lane & 15;
  const int l4 = lane >> 4;

  int a_off[4][2], b_off[2][2];
#pragma unroll
  for (int m = 0; m < 4; ++m) {
    int row = wr * 64 + m * 16 + frow;
#pragma unroll
    for (int kk = 0; kk < 2; ++kk)
      a_off[m][kk] = (row << 6) + ((((kk << 2) + l4) ^ (row & 7)) << 3);
  }
#pragma unroll
  for (int n = 0; n < 2; ++n) {
    int row = wc * 32 + n * 16 + frow;
#pragma unroll
    for (int kk = 0; kk < 2; ++kk)
      b_off[n][kk] = (row << 6) + ((((kk << 2) + l4) ^ (row & 7)) << 3);
  }

  f32x4 acc[4][2];
#pragma unroll
  for (int m = 0; m < 4; ++m)
#pragma unroll
    for (int n = 0; n < 2; ++n) acc[m][n] = (f32x4)0.0f;

  const int dst = tid << 3;
  auto stage = [&](int k0, int c) {
#pragma unroll
    for (int p = 0; p < 2; ++p)
      gload16(gA[p] + k0, &As[c][(p << 12) + dst]);
#pragma unroll
    for (int p = 0; p < 2; ++p)
      gload16(gB[p] + k0, &Bs[c][(p << 12) + dst]);
  };

  const int KT = K >> 6;
  stage(0, 0);
  int cur = 0;
  for (int kt = 0; kt < KT; ++kt) {
    __syncthreads();
    if (kt + 1 < KT) stage((kt + 1) << 6, cur ^ 1);
#pragma unroll
    for (int kk = 0; kk < 2; ++kk) {
      short8 a[4], b[2];
#pragma unroll
      for (int m = 0; m < 4; ++m)
        a[m] = *reinterpret_cast<const short8*>(&As[cur][a_off[m][kk]]);
#pragma unroll
      for (int n = 0; n < 2; ++n)
        b[n] = *reinterpret_cast<const short8*>(&Bs[cur][b_off[n][kk]]);
#pragma unroll
      for (int m = 0; m < 4; ++m)
#pragma unroll
        for (int n = 0; n < 2; ++n)
          acc[m][n] = __builtin_amdgcn_mfma_f32_16x16x32_bf16(a[m], b[n], acc[m][n], 0, 0, 0);
    }
    cur ^= 1;
  }

  const int rbase = l4 << 2;
  const int cbase = frow;
#pragma unroll
  for (int m = 0; m < 4; ++m) {
#pragma unroll
    for (int r = 0; r < 4; ++r) {
      int lr = wr * 64 + (m << 4) + rbase + r;
      int grow = mt * 128 + lr;
      if (EPI >= 2 && grow >= cnt) continue;
      float wv = 1.0f;
      if constexpr (EPI == 2) wv = w_g[obase + grow];
      const int* pm = nullptr;
      if constexpr (EPI == 1) pm = pos_map + grow * TOPK;
#pragma unroll
      for (int n = 0; n < 2; ++n) {
        int gc = nt * 128 + wc * 32 + (n << 4) + cbase;
        float v = acc[m][n][r];
        if constexpr (EPI == 0) {
          float tpos = fmaxf(v, 0.0f);
          Cb[(size_t)grow * N + gc] = f2bf(tpos * tpos);
        } else if constexpr (EPI == 1) {
          v += bf2f(Rd[(size_t)pm[0] * H_DIM + gc]);
          v += bf2f(Rd[(size_t)pm[1] * H_DIM + gc]);
          v += bf2f(Rd[(size_t)pm[2] * H_DIM + gc]);
          v += bf2f(Rd[(size_t)pm[3] * H_DIM + gc]);
          Cf[(size_t)grow * N + gc] = v;
        } else if constexpr (EPI == 2) {
          float tpos = fmaxf(v, 0.0f);
          Cb[(size_t)(obase + grow) * I_DIM + gc] = f2bf(tpos * tpos * wv);
        } else {
          Cb[(size_t)(obase + grow) * N + gc] = f2bf(v);
        }
      }
    }
  }
}

// ---------------- launch ----------------
extern "C" void kernel_launch(void* const* d_in, const int* in_sizes, int n_in,
                              void* d_out, int out_size, void* d_ws, size_t ws_size,
                              hipStream_t stream) {
  const float* x = (const float*)d_in[0];
  const float* rw = (const float*)d_in[1];
  const float* bias = (const float*)d_in[2];
  const float* w_up = (const float*)d_in[3];
  const float* w_down = (const float*)d_in[4];
  const float* ws_up = (const float*)d_in[5];
  const float* ws_down = (const float*)d_in[6];
  float* out = (float*)d_out;

  uint8_t* wsb = (uint8_t*)d_ws;
  size_t off = 0;
  auto alloc = [&](size_t bytes) {
    void* p = wsb + off;
    off += (bytes + 255) & ~(size_t)255;
    return p;
  };
  u16* x_bf = (u16*)alloc((size_t)T_TOK * H_DIM * 2);
  u16* wsup_bf = (u16*)alloc((size_t)IS_DIM * H_DIM * 2);
  u16* wsdn_bf = (u16*)alloc((size_t)H_DIM * IS_DIM * 2);
  u16* wup_bf = (u16*)alloc((size_t)E_NUM * I_DIM * H_DIM * 2);
  u16* wdn_bf = (u16*)alloc((size_t)E_NUM * H_DIM * I_DIM * 2);
  u16* hs = (u16*)alloc((size_t)T_TOK * IS_DIM * 2);
  u16* hp = (u16*)alloc((size_t)(T_TOK * TOPK + 128) * I_DIM * 2);
  u16* hp_down = (u16*)alloc((size_t)(T_TOK * TOPK + 128) * H_DIM * 2);
  int* counts = (int*)alloc(64);
  int* offsets = (int*)alloc(128);
  int* tok_g = (int*)alloc((size_t)(T_TOK * TOPK) * 4);
  float* w_g = (float*)alloc((size_t)(T_TOK * TOPK) * 4);
  int* pos_map = (int*)alloc((size_t)(T_TOK * TOPK) * 4);
  int* tidx_buf = (int*)alloc((size_t)T_TOK * TOPK * 4);
  float* tw_buf = (float*)alloc((size_t)T_TOK * TOPK * 4);
  int* partial = (int*)alloc((size_t)NCHUNK * E_NUM * 4);
  int* chunk_base = (int*)alloc((size_t)NCHUNK * E_NUM * 4);

  int n4;
  n4 = T_TOK * H_DIM / 4;
  cvt_bf16_kernel<<<(n4 + 255) / 256, 256, 0, stream>>>(x, x_bf, n4);
  n4 = IS_DIM * H_DIM / 4;
  cvt_bf16_kernel<<<(n4 + 255) / 256, 256, 0, stream>>>(ws_up, wsup_bf, n4);
  n4 = H_DIM * IS_DIM / 4;
  cvt_bf16_kernel<<<(n4 + 255) / 256, 256, 0, stream>>>(ws_down, wsdn_bf, n4);
  n4 = E_NUM * I_DIM * H_DIM / 4;
  cvt_bf16_kernel<<<(n4 + 255) / 256, 256, 0, stream>>>(w_up, wup_bf, n4);
  n4 = E_NUM * H_DIM * I_DIM / 4;
  cvt_bf16_kernel<<<(n4 + 255) / 256, 256, 0, stream>>>(w_down, wdn_bf, n4);

  route_kernel<<<T_TOK / 4, 256, 0, stream>>>(x, rw, bias, tidx_buf, tw_buf);
  hist_kernel<<<NCHUNK, 256, 0, stream>>>(tidx_buf, partial);
  prefix2_kernel<<<1, 256, 0, stream>>>(partial, chunk_base, counts, offsets);
  scatter2_kernel<<<NCHUNK, 256, 0, stream>>>(tidx_buf, tw_buf, chunk_base,
                                              tok_g, w_g, pos_map);

  // shared up: [T,H] x [IS,H]^T -> hs (relu^2, bf16)
  gemm_bt<0><<<(T_TOK / 128) * (IS_DIM / 128), 512, 0, stream>>>(
      x_bf, wsup_bf, nullptr, hs, T_TOK, IS_DIM, H_DIM,
      nullptr, nullptr, nullptr, nullptr, nullptr, nullptr);
  // routed up: gathered x rows x w_up[e]^T -> hp (relu^2 * w, bf16)
  gemm_bt<2><<<E_NUM * MAXMT * (I_DIM / 128), 512, 0, stream>>>(
      x_bf, wup_bf, nullptr, hp, T_TOK, I_DIM, H_DIM,
      counts, offsets, tok_g, w_g, nullptr, nullptr);
  // routed down: hp x w_down[e]^T -> hp_down bf16 (plain store)
  gemm_bt<3><<<E_NUM * MAXMT * (H_DIM / 128), 512, 0, stream>>>(
      hp, wdn_bf, nullptr, hp_down, T_TOK, H_DIM, I_DIM,
      counts, offsets, tok_g, w_g, nullptr, nullptr);
  // shared down + routed gather: hs x [H,IS]^T + sum_k hp_down -> out
  gemm_bt<1><<<(T_TOK / 128) * (H_DIM / 128), 512, 0, stream>>>(
      hs, wsdn_bf, out, nullptr, T_TOK, H_DIM, IS_DIM,
      nullptr, nullptr, nullptr, nullptr, pos_map, hp_down);
}

// Round 6
// 206.885 us; speedup vs baseline: 2.0980x; 1.0058x over previous
//
#include <hip/hip_runtime.h>
#include <stdint.h>

#define T_TOK 4096
#define H_DIM 1024
#define E_NUM 16
#define I_DIM 512
#define IS_DIM 2048
#define TOPK 4
#define NGRP 4
#define GSZ 4
#define MAXMT 32
#define NCHUNK 64  // (T_TOK*TOPK)/256

// cvt segment boundaries in float4 units
#define S0 1048576
#define S1 1572864
#define S2 2097152
#define S3 4194304
#define S4 6291456

typedef unsigned short u16;
typedef __attribute__((ext_vector_type(8))) short short8;
typedef __attribute__((ext_vector_type(4))) float f32x4;

__device__ __forceinline__ void gload16(const void* g, void* l) {
  __builtin_amdgcn_global_load_lds(
      (const __attribute__((address_space(1))) void*)g,
      (__attribute__((address_space(3))) void*)l, 16, 0, 0);
}

__device__ __forceinline__ u16 f2bf(float f) {
  union { float f; uint32_t u; } v; v.f = f;
  uint32_t u = v.u;
  uint32_t r = (u + 0x7fffu + ((u >> 16) & 1u)) >> 16;
  return (u16)r;
}

__device__ __forceinline__ float bf2f(u16 h) {
  union { uint32_t u; float f; } v; v.u = ((uint32_t)h) << 16;
  return v.f;
}

// ---------------- fused fp32 -> bf16 conversion (5 segments) --------------
__global__ __launch_bounds__(256) void cvt_all_kernel(
    const float* __restrict__ x, const float* __restrict__ wsu,
    const float* __restrict__ wsd, const float* __restrict__ wu,
    const float* __restrict__ wd,
    u16* __restrict__ xb, u16* __restrict__ wsub, u16* __restrict__ wsdb,
    u16* __restrict__ wub, u16* __restrict__ wdb) {
  int i = blockIdx.x * 256 + threadIdx.x;
  const float4* src; ushort4* dst; int base;
  if (i < S0)      { src = (const float4*)x;   dst = (ushort4*)xb;   base = 0;  }
  else if (i < S1) { src = (const float4*)wsu; dst = (ushort4*)wsub; base = S0; }
  else if (i < S2) { src = (const float4*)wsd; dst = (ushort4*)wsdb; base = S1; }
  else if (i < S3) { src = (const float4*)wu;  dst = (ushort4*)wub;  base = S2; }
  else             { src = (const float4*)wd;  dst = (ushort4*)wdb;  base = S3; }
  float4 v = src[i - base];
  ushort4 o;
  o.x = f2bf(v.x); o.y = f2bf(v.y); o.z = f2bf(v.z); o.w = f2bf(v.w);
  dst[i - base] = o;
}

// ---------------- routing: per-token top-4 (no atomics) ----------------
__global__ __launch_bounds__(256) void route_kernel(
    const float* __restrict__ x, const float* __restrict__ rw,
    const float* __restrict__ bias, int* __restrict__ tidx_out,
    float* __restrict__ tw_out) {
  const int wave = threadIdx.x >> 6;
  const int lane = threadIdx.x & 63;
  const int t = blockIdx.x * 4 + wave;

  const float4* xr = reinterpret_cast<const float4*>(x + (size_t)t * H_DIM);
  const float4* rw4 = reinterpret_cast<const float4*>(rw);
  float4 xv[4];
#pragma unroll
  for (int j = 0; j < 4; ++j) xv[j] = xr[lane + j * 64];

  double acc[E_NUM];
#pragma unroll
  for (int e = 0; e < E_NUM; ++e) {
    double a = 0.0;
#pragma unroll
    for (int j = 0; j < 4; ++j) {
      float4 w = rw4[e * 256 + lane + j * 64];
      a += (double)xv[j].x * (double)w.x;
      a += (double)xv[j].y * (double)w.y;
      a += (double)xv[j].z * (double)w.z;
      a += (double)xv[j].w * (double)w.w;
    }
    acc[e] = a;
  }
#pragma unroll
  for (int e = 0; e < E_NUM; ++e) {
#pragma unroll
    for (int off = 32; off; off >>= 1) acc[e] += __shfl_xor(acc[e], off);
  }
  if (lane == 0) {
    float scores[E_NUM], sfc[E_NUM];
#pragma unroll
    for (int e = 0; e < E_NUM; ++e) {
      scores[e] = 1.0f / (1.0f + expf((float)(-acc[e])));
      sfc[e] = scores[e] + bias[e];
    }
    float gs[NGRP];
#pragma unroll
    for (int g = 0; g < NGRP; ++g) {
      float m1 = -1e30f, m2 = -1e30f;
#pragma unroll
      for (int j = 0; j < GSZ; ++j) {
        float v = sfc[g * GSZ + j];
        if (v > m1) { m2 = m1; m1 = v; } else if (v > m2) { m2 = v; }
      }
      gs[g] = m1 + m2;
    }
    int g1 = 0;
    for (int g = 1; g < NGRP; ++g) if (gs[g] > gs[g1]) g1 = g;
    int g2 = -1;
    for (int g = 0; g < NGRP; ++g) {
      if (g == g1) continue;
      if (g2 < 0 || gs[g] > gs[g2]) g2 = g;
    }
    float masked[E_NUM];
#pragma unroll
    for (int e = 0; e < E_NUM; ++e) {
      int g = e / GSZ;
      masked[e] = (g == g1 || g == g2) ? sfc[e] : 0.0f;
    }
    int tidx[TOPK]; float tw[TOPK];
#pragma unroll
    for (int k = 0; k < TOPK; ++k) {
      int best = 0; float bv = masked[0];
      for (int e = 1; e < E_NUM; ++e)
        if (masked[e] > bv) { bv = masked[e]; best = e; }
      tidx[k] = best; tw[k] = scores[best]; masked[best] = -1e30f;
    }
    float s = tw[0] + tw[1] + tw[2] + tw[3] + 1e-20f;
#pragma unroll
    for (int k = 0; k < TOPK; ++k) {
      tidx_out[t * TOPK + k] = tidx[k];
      tw_out[t * TOPK + k] = tw[k] / s * 2.5f;
    }
  }
}

// ---------------- chunk histogram (64 blocks, one barrier) ----------------
__global__ __launch_bounds__(256) void hist_kernel(const int* __restrict__ tidx,
                                                   int* __restrict__ partial) {
  const int c = blockIdx.x;
  const int tid = threadIdx.x;
  const int lane = tid & 63;
  const int w = tid >> 6;
  __shared__ int h[4][E_NUM];
  const int e = tidx[c * 256 + tid];
#pragma unroll
  for (int ee = 0; ee < E_NUM; ++ee) {
    unsigned long long b = __ballot(e == ee);
    if (lane == 0) h[w][ee] = __popcll(b);
  }
  __syncthreads();
  if (tid < E_NUM)
    partial[c * E_NUM + tid] = h[0][tid] + h[1][tid] + h[2][tid] + h[3][tid];
}

// ------- per-expert chunk bases + expert offsets (1 block) -------
__global__ __launch_bounds__(256) void prefix2_kernel(
    const int* __restrict__ partial, int* __restrict__ chunk_base,
    int* __restrict__ counts, int* __restrict__ offsets) {
  __shared__ int tot[E_NUM];
  __shared__ int offs[E_NUM];
  const int tid = threadIdx.x;
  if (tid < E_NUM) {
    int run = 0;
    for (int c = 0; c < NCHUNK; ++c) {
      chunk_base[c * E_NUM + tid] = run;
      run += partial[c * E_NUM + tid];
    }
    tot[tid] = run;
    counts[tid] = run;
  }
  __syncthreads();
  if (tid == 0) {
    int s = 0;
    for (int e = 0; e < E_NUM; ++e) { offs[e] = s; offsets[e] = s; s += tot[e]; }
    offsets[E_NUM] = s;
  }
  __syncthreads();
  for (int i = tid; i < NCHUNK * E_NUM; i += 256)
    chunk_base[i] += offs[i & 15];
}

// ---------------- scatter (64 blocks, one barrier) ----------------
__global__ __launch_bounds__(256) void scatter2_kernel(
    const int* __restrict__ tidx, const float* __restrict__ tw,
    const int* __restrict__ chunk_base,
    int* __restrict__ tok_g, float* __restrict__ w_g, int* __restrict__ pos_map) {
  const int c = blockIdx.x;
  const int tid = threadIdx.x;
  const int lane = tid & 63;
  const int w = tid >> 6;
  __shared__ int h[4][E_NUM];
  const int i = c * 256 + tid;
  const int e = tidx[i];
  int pre = 0;
#pragma unroll
  for (int ee = 0; ee < E_NUM; ++ee) {
    unsigned long long b = __ballot(e == ee);
    if (lane == 0) h[w][ee] = __popcll(b);
    if (ee == e) pre = __popcll(b & ((1ull << lane) - 1ull));
  }
  __syncthreads();
  int rank = pre;
  for (int ww = 0; ww < w; ++ww) rank += h[ww][e];
  const int pos = chunk_base[c * E_NUM + e] + rank;
  tok_g[pos] = i >> 2;
  w_g[pos] = tw[i];
  pos_map[i] = pos;
}

// ---- bf16 MFMA GEMM: C = A * B^T -----------------------------------------
// 128x128 tile, 4 waves of 64x64, BK=32, NB=3 LDS buffers, counted vmcnt(4),
// raw s_barrier (no vmcnt(0) drain in main loop), depth-2 prefetch.
// EPI 0: shared-up   : C=hs bf16, relu^2
// EPI 1: shared-down : out[t] = acc + sum_k bf2f(Rd[pos_map[t*4+k]])
// EPI 2: routed-up   : A gathered via tok_g, C=hp bf16, relu^2 * w
// EPI 3: routed-down : C=Rd bf16 plain store at row obase+grow
template <int EPI>
__global__ __launch_bounds__(256, 3) void gemm_bt(
    const u16* __restrict__ Abase, const u16* __restrict__ Bbase,
    float* __restrict__ Cf, u16* __restrict__ Cb,
    int M, int N, int K,
    const int* __restrict__ counts, const int* __restrict__ offsets,
    const int* __restrict__ tok_g, const float* __restrict__ w_g,
    const int* __restrict__ pos_map, const u16* __restrict__ Rd) {
  __shared__ __align__(16) u16 As[3][128 * 32];
  __shared__ __align__(16) u16 Bs[3][128 * 32];

  const int NT = N >> 7;
  int mt, nt, cnt = M, obase = 0;
  const u16* A = Abase;
  const u16* B = Bbase;

  if constexpr (EPI <= 1) {
    mt = blockIdx.x / NT;
    nt = blockIdx.x - mt * NT;
  } else {
    const int per_e = MAXMT * NT;
    int e = blockIdx.x / per_e;
    int r = blockIdx.x - e * per_e;
    mt = r / NT;
    nt = r - mt * NT;
    cnt = counts[e];
    if (mt * 128 >= cnt) return;
    obase = offsets[e];
    if constexpr (EPI == 2) {
      B = Bbase + (size_t)e * (I_DIM * H_DIM);
    } else {
      A = Abase + (size_t)obase * I_DIM;
      B = Bbase + (size_t)e * (H_DIM * I_DIM);
    }
  }

  const int tid = threadIdx.x;
  // staging: pass p covers rows p*64 + (tid>>2); phys 16B-slot = tid&3;
  // logical slot = phys ^ ((row>>1)&3)  (involution; LDS dest stays linear)
  const int srow = tid >> 2;
  const int sphys = tid & 3;
  const u16* gA[2];
  const u16* gB[2];
#pragma unroll
  for (int p = 0; p < 2; ++p) {
    int rloc = p * 64 + srow;
    int ks = ((sphys ^ ((rloc >> 1) & 3)) << 3);
    int am = mt * 128 + rloc;
    if constexpr (EPI == 2) {
      int tk = tok_g[obase + ((am < cnt) ? am : 0)];
      gA[p] = Abase + (size_t)tk * H_DIM + ks;
    } else if constexpr (EPI == 3) {
      gA[p] = A + (size_t)((am < cnt) ? am : 0) * K + ks;
    } else {
      gA[p] = A + (size_t)am * K + ks;
    }
    gB[p] = B + (size_t)(nt * 128 + rloc) * K + ks;
  }

  const int wave = tid >> 6;
  const int lane = tid & 63;
  const int wr = wave >> 1;      // 0..1 row-block of 64
  const int wc = wave & 1;       // 0..1 col-block of 64
  const int frow = lane & 15;
  const int l4 = lane >> 4;

  // fragment read offsets (u16 units), swizzle-consistent
  int a_off[4], b_off[4];
#pragma unroll
  for (int m = 0; m < 4; ++m) {
    int row = wr * 64 + m * 16 + frow;
    a_off[m] = (row << 5) + ((l4 ^ ((row >> 1) & 3)) << 3);
  }
#pragma unroll
  for (int n = 0; n < 4; ++n) {
    int row = wc * 64 + n * 16 + frow;
    b_off[n] = (row << 5) + ((l4 ^ ((row >> 1) & 3)) << 3);
  }

  f32x4 acc[4][4];
#pragma unroll
  for (int m = 0; m < 4; ++m)
#pragma unroll
    for (int n = 0; n < 4; ++n) acc[m][n] = (f32x4)0.0f;

  const int dst = tid << 3;  // u16 offset within pass (linear)
  auto stage = [&](int k0, int c) {
#pragma unroll
    for (int p = 0; p < 2; ++p)
      gload16(gA[p] + k0, &As[c][(p << 11) + dst]);
#pragma unroll
    for (int p = 0; p < 2; ++p)
      gload16(gB[p] + k0, &Bs[c][(p << 11) + dst]);
  };

  const int KT = K >> 5;
  stage(0, 0);
  stage(32, 1);
  int cb = 0, sb = 2;  // compute buffer (kt%3), stage buffer ((kt+2)%3)
  for (int kt = 0; kt < KT; ++kt) {
    if (kt < KT - 1) {
      asm volatile("s_waitcnt vmcnt(4)" ::: "memory");
    } else {
      asm volatile("s_waitcnt vmcnt(0)" ::: "memory");
    }
    __builtin_amdgcn_s_barrier();
    __builtin_amdgcn_sched_barrier(0);
    if (kt + 2 < KT) stage((kt + 2) << 5, sb);
    const u16* Ab = &As[cb][0];
    const u16* Bb = &Bs[cb][0];
    short8 a[4], b[4];
#pragma unroll
    for (int m = 0; m < 4; ++m)
      a[m] = *reinterpret_cast<const short8*>(Ab + a_off[m]);
#pragma unroll
    for (int n = 0; n < 4; ++n)
      b[n] = *reinterpret_cast<const short8*>(Bb + b_off[n]);
    __builtin_amdgcn_s_setprio(1);
#pragma unroll
    for (int m = 0; m < 4; ++m)
#pragma unroll
      for (int n = 0; n < 4; ++n)
        acc[m][n] = __builtin_amdgcn_mfma_f32_16x16x32_bf16(a[m], b[n], acc[m][n], 0, 0, 0);
    __builtin_amdgcn_s_setprio(0);
    cb = (cb == 2) ? 0 : cb + 1;
    sb = (sb == 2) ? 0 : sb + 1;
  }

  const int rbase = l4 << 2;
  const int cbase = frow;
#pragma unroll
  for (int m = 0; m < 4; ++m) {
#pragma unroll
    for (int r = 0; r < 4; ++r) {
      int lr = wr * 64 + (m << 4) + rbase + r;
      int grow = mt * 128 + lr;
      if (EPI >= 2 && grow >= cnt) continue;
      float wv = 1.0f;
      if constexpr (EPI == 2) wv = w_g[obase + grow];
      const int* pm = nullptr;
      if constexpr (EPI == 1) pm = pos_map + grow * TOPK;
#pragma unroll
      for (int n = 0; n < 4; ++n) {
        int gc = nt * 128 + wc * 64 + (n << 4) + cbase;
        float v = acc[m][n][r];
        if constexpr (EPI == 0) {
          float tpos = fmaxf(v, 0.0f);
          Cb[(size_t)grow * N + gc] = f2bf(tpos * tpos);
        } else if constexpr (EPI == 1) {
          v += bf2f(Rd[(size_t)pm[0] * H_DIM + gc]);
          v += bf2f(Rd[(size_t)pm[1] * H_DIM + gc]);
          v += bf2f(Rd[(size_t)pm[2] * H_DIM + gc]);
          v += bf2f(Rd[(size_t)pm[3] * H_DIM + gc]);
          Cf[(size_t)grow * N + gc] = v;
        } else if constexpr (EPI == 2) {
          float tpos = fmaxf(v, 0.0f);
          Cb[(size_t)(obase + grow) * I_DIM + gc] = f2bf(tpos * tpos * wv);
        } else {
          Cb[(size_t)(obase + grow) * N + gc] = f2bf(v);
        }
      }
    }
  }
}

// ---------------- launch ----------------
extern "C" void kernel_launch(void* const* d_in, const int* in_sizes, int n_in,
                              void* d_out, int out_size, void* d_ws, size_t ws_size,
                              hipStream_t stream) {
  const float* x = (const float*)d_in[0];
  const float* rw = (const float*)d_in[1];
  const float* bias = (const float*)d_in[2];
  const float* w_up = (const float*)d_in[3];
  const float* w_down = (const float*)d_in[4];
  const float* ws_up = (const float*)d_in[5];
  const float* ws_down = (const float*)d_in[6];
  float* out = (float*)d_out;

  uint8_t* wsb = (uint8_t*)d_ws;
  size_t off = 0;
  auto alloc = [&](size_t bytes) {
    void* p = wsb + off;
    off += (bytes + 255) & ~(size_t)255;
    return p;
  };
  u16* x_bf = (u16*)alloc((size_t)T_TOK * H_DIM * 2);
  u16* wsup_bf = (u16*)alloc((size_t)IS_DIM * H_DIM * 2);
  u16* wsdn_bf = (u16*)alloc((size_t)H_DIM * IS_DIM * 2);
  u16* wup_bf = (u16*)alloc((size_t)E_NUM * I_DIM * H_DIM * 2);
  u16* wdn_bf = (u16*)alloc((size_t)E_NUM * H_DIM * I_DIM * 2);
  u16* hs = (u16*)alloc((size_t)T_TOK * IS_DIM * 2);
  u16* hp = (u16*)alloc((size_t)(T_TOK * TOPK + 128) * I_DIM * 2);
  u16* hp_down = (u16*)alloc((size_t)(T_TOK * TOPK + 128) * H_DIM * 2);
  int* counts = (int*)alloc(64);
  int* offsets = (int*)alloc(128);
  int* tok_g = (int*)alloc((size_t)(T_TOK * TOPK) * 4);
  float* w_g = (float*)alloc((size_t)(T_TOK * TOPK) * 4);
  int* pos_map = (int*)alloc((size_t)(T_TOK * TOPK) * 4);
  int* tidx_buf = (int*)alloc((size_t)T_TOK * TOPK * 4);
  float* tw_buf = (float*)alloc((size_t)T_TOK * TOPK * 4);
  int* partial = (int*)alloc((size_t)NCHUNK * E_NUM * 4);
  int* chunk_base = (int*)alloc((size_t)NCHUNK * E_NUM * 4);

  cvt_all_kernel<<<S4 / 256, 256, 0, stream>>>(
      x, ws_up, ws_down, w_up, w_down,
      x_bf, wsup_bf, wsdn_bf, wup_bf, wdn_bf);

  route_kernel<<<T_TOK / 4, 256, 0, stream>>>(x, rw, bias, tidx_buf, tw_buf);
  hist_kernel<<<NCHUNK, 256, 0, stream>>>(tidx_buf, partial);
  prefix2_kernel<<<1, 256, 0, stream>>>(partial, chunk_base, counts, offsets);
  scatter2_kernel<<<NCHUNK, 256, 0, stream>>>(tidx_buf, tw_buf, chunk_base,
                                              tok_g, w_g, pos_map);

  // shared up: [T,H] x [IS,H]^T -> hs (relu^2, bf16)
  gemm_bt<0><<<(T_TOK / 128) * (IS_DIM / 128), 256, 0, stream>>>(
      x_bf, wsup_bf, nullptr, hs, T_TOK, IS_DIM, H_DIM,
      nullptr, nullptr, nullptr, nullptr, nullptr, nullptr);
  // routed up: gathered x rows x w_up[e]^T -> hp (relu^2 * w, bf16)
  gemm_bt<2><<<E_NUM * MAXMT * (I_DIM / 128), 256, 0, stream>>>(
      x_bf, wup_bf, nullptr, hp, T_TOK, I_DIM, H_DIM,
      counts, offsets, tok_g, w_g, nullptr, nullptr);
  // routed down: hp x w_down[e]^T -> hp_down bf16 (plain store)
  gemm_bt<3><<<E_NUM * MAXMT * (H_DIM / 128), 256, 0, stream>>>(
      hp, wdn_bf, nullptr, hp_down, T_TOK, H_DIM, I_DIM,
      counts, offsets, tok_g, w_g, nullptr, nullptr);
  // shared down + routed gather: hs x [H,IS]^T + sum_k hp_down -> out
  gemm_bt<1><<<(T_TOK / 128) * (H_DIM / 128), 256, 0, stream>>>(
      hs, wsdn_bf, out, nullptr, T_TOK, H_DIM, IS_DIM,
      nullptr, nullptr, nullptr, nullptr, pos_map, hp_down);
}